// Round 1
// baseline (5597.206 us; speedup 1.0000x reference)
//
#include <hip/hip_runtime.h>
#include <hip/hip_bf16.h>
#include <math.h>

#define D_MODEL   1024
#define D_INNER   2048
#define D_STATE   128
#define NHEADS    32
#define HEADDIM   64
#define DCONV     4
#define CONV_DIM  (D_INNER + 2 * D_STATE)            // 2304
#define D_IN_PROJ (2 * D_INNER + 2 * D_STATE + NHEADS) // 4384
#define NBLOCKS   4
#define BATCH     4
#define SEQ       512
#define NTOK      (BATCH * SEQ)                      // 2048
#define STATE_IN  510

// ---------------------------------------------------------------------------
// concat [x, steps_left, current_r] -> hcat [NTOK, 512]
// ---------------------------------------------------------------------------
__global__ void concat_kernel(const float* __restrict__ x,
                              const float* __restrict__ steps,
                              const float* __restrict__ curr,
                              float* __restrict__ hcat)
{
    int idx = blockIdx.x * 256 + threadIdx.x;           // over NTOK*512
    if (idx >= NTOK * 512) return;
    int bl = idx >> 9;            // token
    int c  = idx & 511;
    float v;
    if (c < STATE_IN)      v = x[(size_t)bl * STATE_IN + c];
    else if (c == STATE_IN) v = steps[bl];
    else                    v = curr[bl];
    hcat[idx] = v;
}

// ---------------------------------------------------------------------------
// fp32 SGEMM: C[M,N] = act(A[M,K] @ B[K,N] + bias)
// 128x128 tile, BK=8, 256 threads, 8x8 per thread. K % 8 == 0, N % 4 == 0.
// ---------------------------------------------------------------------------
__global__ __launch_bounds__(256)
void sgemm_kernel(const float* __restrict__ A, const float* __restrict__ B,
                  const float* __restrict__ bias, float* __restrict__ C,
                  int M, int N, int K, int relu)
{
    __shared__ float As[8][128];
    __shared__ float Bs[8][128];
    int tid = threadIdx.x;
    int tx = tid & 15;
    int ty = tid >> 4;
    int m0 = blockIdx.y * 128;
    int n0 = blockIdx.x * 128;

    float acc[8][8];
#pragma unroll
    for (int i = 0; i < 8; ++i)
#pragma unroll
        for (int j = 0; j < 8; ++j) acc[i][j] = 0.f;

    int ar = tid >> 1;            // 0..127 : row in A tile
    int ac = (tid & 1) * 4;       // 0 or 4 : col in A tile
    int br = tid >> 5;            // 0..7   : row in B tile
    int bc = (tid & 31) * 4;      // 0..124 : col in B tile

    for (int k0 = 0; k0 < K; k0 += 8) {
        float4 av = make_float4(0.f, 0.f, 0.f, 0.f);
        int arow = m0 + ar;
        if (arow < M) av = *(const float4*)(A + (size_t)arow * K + k0 + ac);
        float4 bv = make_float4(0.f, 0.f, 0.f, 0.f);
        int bcol = n0 + bc;
        if (bcol < N) bv = *(const float4*)(B + (size_t)(k0 + br) * N + bcol);
        __syncthreads();
        As[ac + 0][ar] = av.x;
        As[ac + 1][ar] = av.y;
        As[ac + 2][ar] = av.z;
        As[ac + 3][ar] = av.w;
        *(float4*)&Bs[br][bc] = bv;
        __syncthreads();
#pragma unroll
        for (int kk = 0; kk < 8; ++kk) {
            float a[8], b[8];
            *(float4*)&a[0] = *(const float4*)&As[kk][ty * 8];
            *(float4*)&a[4] = *(const float4*)&As[kk][ty * 8 + 4];
            *(float4*)&b[0] = *(const float4*)&Bs[kk][tx * 8];
            *(float4*)&b[4] = *(const float4*)&Bs[kk][tx * 8 + 4];
#pragma unroll
            for (int i = 0; i < 8; ++i)
#pragma unroll
                for (int j = 0; j < 8; ++j)
                    acc[i][j] = fmaf(a[i], b[j], acc[i][j]);
        }
    }

#pragma unroll
    for (int i = 0; i < 8; ++i) {
        int row = m0 + ty * 8 + i;
        if (row >= M) continue;
#pragma unroll
        for (int j = 0; j < 8; ++j) {
            int col = n0 + tx * 8 + j;
            if (col >= N) continue;
            float v = acc[i][j];
            if (bias) v += bias[col];
            if (relu) v = fmaxf(v, 0.f);
            C[(size_t)row * N + col] = v;
        }
    }
}

// ---------------------------------------------------------------------------
// causal depthwise conv1d (k=4) + SiLU over xBC channels of zxbcdt
// zxbcdt: [NTOK, D_IN_PROJ]; out xBCc: [NTOK, CONV_DIM]
// ---------------------------------------------------------------------------
__global__ void conv_silu_kernel(const float* __restrict__ zxbcdt,
                                 const float* __restrict__ cw,   // [CONV_DIM,4]
                                 const float* __restrict__ cb,   // [CONV_DIM]
                                 float* __restrict__ xBCc)
{
    int idx = blockIdx.x * 256 + threadIdx.x;           // over NTOK*CONV_DIM
    if (idx >= NTOK * CONV_DIM) return;
    int c  = idx % CONV_DIM;
    int bl = idx / CONV_DIM;
    int b  = bl >> 9;
    int l  = bl & 511;
    float acc = cb[c];
#pragma unroll
    for (int k = 0; k < DCONV; ++k) {
        int ll = l + k - (DCONV - 1);
        if (ll >= 0)
            acc = fmaf(zxbcdt[(size_t)(b * SEQ + ll) * D_IN_PROJ + D_INNER + c],
                       cw[c * DCONV + k], acc);
    }
    xBCc[idx] = acc / (1.f + expf(-acc));   // silu
}

// ---------------------------------------------------------------------------
// sequential selective scan; 1 block per (batch, head), 512 threads.
// thread t: p = t>>3 (0..63), owns n in [ (t&7)*16, +16 ).
// ---------------------------------------------------------------------------
__global__ __launch_bounds__(512)
void scan_kernel(const float* __restrict__ zxbcdt,   // [NTOK, D_IN_PROJ]
                 const float* __restrict__ xBCc,     // [NTOK, CONV_DIM]
                 const float* __restrict__ dt_bias,  // [NHEADS]
                 const float* __restrict__ A_log,    // [NHEADS]
                 const float* __restrict__ D_skip,   // [NHEADS]
                 float* __restrict__ y)              // [NTOK, D_INNER]
{
    int bh = blockIdx.x;          // 0..127
    int b  = bh >> 5;
    int h  = bh & 31;
    int t  = threadIdx.x;
    int p  = t >> 3;
    int ng = t & 7;
    int n0 = ng * 16;

    __shared__ float Bsh[D_STATE];
    __shared__ float Csh[D_STATE];
    __shared__ float xsh[HEADDIM];

    float dtb = dt_bias[h];
    float A   = -expf(A_log[h]);
    float Dsk = D_skip[h];

    float s[16];
#pragma unroll
    for (int j = 0; j < 16; ++j) s[j] = 0.f;

    for (int l = 0; l < SEQ; ++l) {
        int row = b * SEQ + l;
        const float* xr = xBCc + (size_t)row * CONV_DIM;
        if (t < 128)        Bsh[t]        = xr[D_INNER + t];
        else if (t < 256)   Csh[t - 128]  = xr[D_INNER + D_STATE + (t - 128)];
        else if (t < 320)   xsh[t - 256]  = xr[h * HEADDIM + (t - 256)];
        float dtraw = zxbcdt[(size_t)row * D_IN_PROJ + (D_IN_PROJ - NHEADS) + h] + dtb;
        float dtv = (dtraw > 20.f) ? dtraw : log1pf(expf(dtraw));
        float dA  = expf(dtv * A);
        __syncthreads();

        float xp = xsh[p] * dtv;
        float yp = 0.f;
#pragma unroll
        for (int q = 0; q < 4; ++q) {
            float4 Bv = *(const float4*)&Bsh[n0 + q * 4];
            float4 Cv = *(const float4*)&Csh[n0 + q * 4];
            s[q*4+0] = fmaf(s[q*4+0], dA, xp * Bv.x); yp = fmaf(s[q*4+0], Cv.x, yp);
            s[q*4+1] = fmaf(s[q*4+1], dA, xp * Bv.y); yp = fmaf(s[q*4+1], Cv.y, yp);
            s[q*4+2] = fmaf(s[q*4+2], dA, xp * Bv.z); yp = fmaf(s[q*4+2], Cv.z, yp);
            s[q*4+3] = fmaf(s[q*4+3], dA, xp * Bv.w); yp = fmaf(s[q*4+3], Cv.w, yp);
        }
        yp += __shfl_down(yp, 4, 8);
        yp += __shfl_down(yp, 2, 8);
        yp += __shfl_down(yp, 1, 8);
        if (ng == 0)
            y[(size_t)row * D_INNER + h * HEADDIM + p] = yp + Dsk * xsh[p];
        __syncthreads();
    }
}

// ---------------------------------------------------------------------------
// gated RMSNorm: g = y * silu(z); out = g * rsqrt(mean(g^2)+1e-5) * norm_w
// one block per token, 256 threads, 8 channels each
// ---------------------------------------------------------------------------
__global__ __launch_bounds__(256)
void gated_rmsnorm_kernel(const float* __restrict__ y,
                          const float* __restrict__ zxbcdt,
                          const float* __restrict__ norm_w,   // [D_INNER]
                          float* __restrict__ yn)
{
    int bl = blockIdx.x;
    int t  = threadIdx.x;
    const float* yr = y + (size_t)bl * D_INNER;
    const float* zr = zxbcdt + (size_t)bl * D_IN_PROJ;   // z = first D_INNER chans
    float* outr = yn + (size_t)bl * D_INNER;

    float gv[8];
    float ss = 0.f;
#pragma unroll
    for (int q = 0; q < 8; ++q) {
        int j = t + q * 256;
        float z = zr[j];
        float g = yr[j] * (z / (1.f + expf(-z)));
        gv[q] = g;
        ss += g * g;
    }
    __shared__ float red[256];
    red[t] = ss;
    __syncthreads();
    for (int w = 128; w > 0; w >>= 1) {
        if (t < w) red[t] += red[t + w];
        __syncthreads();
    }
    float rs = rsqrtf(red[0] / (float)D_INNER + 1e-5f);
#pragma unroll
    for (int q = 0; q < 8; ++q) {
        int j = t + q * 256;
        outr[j] = gv[q] * rs * norm_w[j];
    }
}

// ---------------------------------------------------------------------------
// final: out[tok] = dot(t1[tok,:], w2[:,0]) + b2   (w2: [1024,1])
// ---------------------------------------------------------------------------
__global__ __launch_bounds__(256)
void final_dot_kernel(const float* __restrict__ t1,
                      const float* __restrict__ w2,
                      const float* __restrict__ b2,
                      float* __restrict__ out)
{
    int bl = blockIdx.x;
    int t  = threadIdx.x;
    float s = 0.f;
    for (int j = t; j < D_MODEL; j += 256)
        s = fmaf(t1[(size_t)bl * D_MODEL + j], w2[j], s);
    __shared__ float red[256];
    red[t] = s;
    __syncthreads();
    for (int w = 128; w > 0; w >>= 1) {
        if (t < w) red[t] += red[t + w];
        __syncthreads();
    }
    if (t == 0) out[bl] = red[0] + b2[0];
}

// ---------------------------------------------------------------------------
extern "C" void kernel_launch(void* const* d_in, const int* in_sizes, int n_in,
                              void* d_out, int out_size, void* d_ws, size_t ws_size,
                              hipStream_t stream)
{
    const float* x        = (const float*)d_in[0];
    const float* steps    = (const float*)d_in[1];
    const float* curr     = (const float*)d_in[2];
    const float* mi_w1    = (const float*)d_in[3];
    const float* mi_b1    = (const float*)d_in[4];
    const float* mi_w2    = (const float*)d_in[5];
    const float* mi_b2    = (const float*)d_in[6];
    const float* W_in     = (const float*)d_in[7];
    const float* conv_w   = (const float*)d_in[8];
    const float* conv_b   = (const float*)d_in[9];
    const float* dt_bias  = (const float*)d_in[10];
    const float* A_log    = (const float*)d_in[11];
    const float* D_skip   = (const float*)d_in[12];
    const float* norm_w   = (const float*)d_in[13];
    const float* W_out    = (const float*)d_in[14];
    const float* mo_w1    = (const float*)d_in[15];
    const float* mo_b1    = (const float*)d_in[16];
    const float* mo_w2    = (const float*)d_in[17];
    const float* mo_b2    = (const float*)d_in[18];
    float* out = (float*)d_out;

    float* ws = (float*)d_ws;
    float* hcat = ws;                               // 2048*512
    float* t0   = hcat + (size_t)NTOK * 512;        // 2048*512
    float* h    = t0   + (size_t)NTOK * 512;        // 2048*1024
    float* zx   = h    + (size_t)NTOK * D_MODEL;    // 2048*4384
    float* xc   = zx   + (size_t)NTOK * D_IN_PROJ;  // 2048*2304
    float* yb   = xc   + (size_t)NTOK * CONV_DIM;   // 2048*2048
    float* yn   = yb   + (size_t)NTOK * D_INNER;    // 2048*2048
    float* t1   = hcat;                             // reuse (2048*1024 fits in hcat+t0)

    // 1) concat
    concat_kernel<<<(NTOK * 512 + 255) / 256, 256, 0, stream>>>(x, steps, curr, hcat);

    // 2) input MLP
    {
        dim3 g(512 / 128, NTOK / 128);
        sgemm_kernel<<<g, 256, 0, stream>>>(hcat, mi_w1, mi_b1, t0, NTOK, 512, 512, 1);
    }
    {
        dim3 g(D_MODEL / 128, NTOK / 128);
        sgemm_kernel<<<g, 256, 0, stream>>>(t0, mi_w2, mi_b2, h, NTOK, D_MODEL, 512, 0);
    }

    // 3) mamba blocks
    for (int i = 0; i < NBLOCKS; ++i) {
        {
            dim3 g((D_IN_PROJ + 127) / 128, NTOK / 128);
            sgemm_kernel<<<g, 256, 0, stream>>>(h, W_in + (size_t)i * D_MODEL * D_IN_PROJ,
                                                nullptr, zx, NTOK, D_IN_PROJ, D_MODEL, 0);
        }
        conv_silu_kernel<<<(NTOK * CONV_DIM + 255) / 256, 256, 0, stream>>>(
            zx, conv_w + (size_t)i * CONV_DIM * DCONV, conv_b + (size_t)i * CONV_DIM, xc);
        scan_kernel<<<BATCH * NHEADS, 512, 0, stream>>>(
            zx, xc, dt_bias + i * NHEADS, A_log + i * NHEADS, D_skip + i * NHEADS, yb);
        gated_rmsnorm_kernel<<<NTOK, 256, 0, stream>>>(yb, zx, norm_w + (size_t)i * D_INNER, yn);
        {
            dim3 g(D_MODEL / 128, NTOK / 128);
            sgemm_kernel<<<g, 256, 0, stream>>>(yn, W_out + (size_t)i * D_INNER * D_MODEL,
                                                nullptr, h, NTOK, D_MODEL, D_INNER, 0);
        }
    }

    // 4) output MLP
    {
        dim3 g(D_MODEL / 128, NTOK / 128);
        sgemm_kernel<<<g, 256, 0, stream>>>(h, mo_w1, mo_b1, t1, NTOK, D_MODEL, D_MODEL, 1);
    }
    final_dot_kernel<<<NTOK, 256, 0, stream>>>(t1, mo_w2, mo_b2, out);
}

// Round 3
// 1693.056 us; speedup vs baseline: 3.3060x; 3.3060x over previous
//
#include <hip/hip_runtime.h>
#include <hip/hip_bf16.h>
#include <math.h>

#define D_MODEL   1024
#define D_INNER   2048
#define D_STATE   128
#define NHEADS    32
#define HEADDIM   64
#define DCONV     4
#define CONV_DIM  (D_INNER + 2 * D_STATE)              // 2304
#define D_IN_PROJ (2 * D_INNER + 2 * D_STATE + NHEADS) // 4384
#define NBLOCKS   4
#define BATCH     4
#define SEQ       512
#define NTOK      (BATCH * SEQ)                        // 2048
#define STATE_IN  510
#define NPAD_IN   4480                                 // D_IN_PROJ padded to 128

typedef _Float16 half8_t __attribute__((ext_vector_type(8)));
typedef float f32x4_t  __attribute__((ext_vector_type(4)));

__device__ __forceinline__ unsigned short f2h(float f) {
    _Float16 h = (_Float16)f;                  // v_cvt_f16_f32, RNE
    return __builtin_bit_cast(unsigned short, h);
}

// ---------------------------------------------------------------------------
// concat [x, steps_left, current_r] -> hcat [NTOK, 512]
// ---------------------------------------------------------------------------
__global__ void concat_kernel(const float* __restrict__ x,
                              const float* __restrict__ steps,
                              const float* __restrict__ curr,
                              float* __restrict__ hcat)
{
    int idx = blockIdx.x * 256 + threadIdx.x;
    if (idx >= NTOK * 512) return;
    int bl = idx >> 9;
    int c  = idx & 511;
    float v;
    if (c < STATE_IN)       v = x[(size_t)bl * STATE_IN + c];
    else if (c == STATE_IN) v = steps[bl];
    else                    v = curr[bl];
    hcat[idx] = v;
}

// ---------------------------------------------------------------------------
// weight transpose + fp16 convert:  W[K,N] fp32 -> WT[Npad,K] fp16
// 32x32 tiles; N % 32 == 0, K % 32 == 0; pad rows (n >= N) written as zero.
// ---------------------------------------------------------------------------
__global__ __launch_bounds__(256)
void transpose_f16_kernel(const float* __restrict__ W, unsigned short* __restrict__ WT,
                          int K, int N)
{
    __shared__ unsigned short tile[32][36];
    int n0 = blockIdx.x * 32, k0 = blockIdx.y * 32;
    int t = threadIdx.x;
    int kl = t >> 3, nl = (t & 7) * 4;
    float4 v = make_float4(0.f, 0.f, 0.f, 0.f);
    if (n0 < N) v = *(const float4*)(W + (size_t)(k0 + kl) * N + n0 + nl);
    tile[nl + 0][kl] = f2h(v.x);
    tile[nl + 1][kl] = f2h(v.y);
    tile[nl + 2][kl] = f2h(v.z);
    tile[nl + 3][kl] = f2h(v.w);
    __syncthreads();
    int nl2 = t >> 3, kl2 = (t & 7) * 4;
    ushort4 o;
    o.x = tile[nl2][kl2 + 0];
    o.y = tile[nl2][kl2 + 1];
    o.z = tile[nl2][kl2 + 2];
    o.w = tile[nl2][kl2 + 3];
    *(ushort4*)(WT + (size_t)(n0 + nl2) * K + k0 + kl2) = o;
}

// ---------------------------------------------------------------------------
// fp16 MFMA GEMM: C[M,N] = act(A[M,K] @ B[K,N] + bias)
// A fp32 row-major (converted to fp16 on stage); B pre-transposed fp16 WT[Npad,K].
// 128x128 tile, BK=32, 256 threads (4 waves, 2x2), 16x16x32 MFMA, 4x4 tiles/wave.
// M % 128 == 0, K % 32 == 0. Cols >= N guarded (WT pad rows are zero).
// ---------------------------------------------------------------------------
#define LDSA_STRIDE 40   // 32 + 8 pad
__global__ __launch_bounds__(256)
void mfma_gemm_kernel(const float* __restrict__ A, const unsigned short* __restrict__ BT,
                      const float* __restrict__ bias, float* __restrict__ C,
                      int N, int K, int relu)
{
    __shared__ unsigned short Al[128 * LDSA_STRIDE];
    __shared__ unsigned short Bl[128 * LDSA_STRIDE];
    const int tid  = threadIdx.x;
    const int lane = tid & 63;
    const int wave = tid >> 6;
    const int wr   = (wave >> 1) * 64, wc = (wave & 1) * 64;
    const int g    = lane >> 4, l16 = lane & 15;
    const int m0   = blockIdx.y * 128, n0 = blockIdx.x * 128;
    const int arow = tid >> 1;
    const int ak   = (tid & 1) * 16;

    f32x4_t acc[4][4];
    const f32x4_t zero = {0.f, 0.f, 0.f, 0.f};
#pragma unroll
    for (int i = 0; i < 4; ++i)
#pragma unroll
        for (int j = 0; j < 4; ++j) acc[i][j] = zero;

    const float*          aptr = A  + (size_t)(m0 + arow) * K + ak;
    const unsigned short* bptr = BT + (size_t)(n0 + arow) * K + ak;
    unsigned short* adst = &Al[arow * LDSA_STRIDE + ak];
    unsigned short* bdst = &Bl[arow * LDSA_STRIDE + ak];

    for (int k0 = 0; k0 < K; k0 += 32) {
        float4 v0 = *(const float4*)(aptr + k0);
        float4 v1 = *(const float4*)(aptr + k0 + 4);
        float4 v2 = *(const float4*)(aptr + k0 + 8);
        float4 v3 = *(const float4*)(aptr + k0 + 12);
        uint4  b0 = *(const uint4*)(bptr + k0);
        uint4  b1 = *(const uint4*)(bptr + k0 + 8);
        __syncthreads();   // previous iter's frag reads done
        unsigned int p0 = f2h(v0.x) | ((unsigned int)f2h(v0.y) << 16);
        unsigned int p1 = f2h(v0.z) | ((unsigned int)f2h(v0.w) << 16);
        unsigned int p2 = f2h(v1.x) | ((unsigned int)f2h(v1.y) << 16);
        unsigned int p3 = f2h(v1.z) | ((unsigned int)f2h(v1.w) << 16);
        unsigned int p4 = f2h(v2.x) | ((unsigned int)f2h(v2.y) << 16);
        unsigned int p5 = f2h(v2.z) | ((unsigned int)f2h(v2.w) << 16);
        unsigned int p6 = f2h(v3.x) | ((unsigned int)f2h(v3.y) << 16);
        unsigned int p7 = f2h(v3.z) | ((unsigned int)f2h(v3.w) << 16);
        ((uint4*)adst)[0] = make_uint4(p0, p1, p2, p3);
        ((uint4*)adst)[1] = make_uint4(p4, p5, p6, p7);
        ((uint4*)bdst)[0] = b0;
        ((uint4*)bdst)[1] = b1;
        __syncthreads();
        half8_t af[4], bfr[4];
#pragma unroll
        for (int ti = 0; ti < 4; ++ti)
            af[ti] = *(const half8_t*)&Al[(wr + ti * 16 + l16) * LDSA_STRIDE + g * 8];
#pragma unroll
        for (int tj = 0; tj < 4; ++tj)
            bfr[tj] = *(const half8_t*)&Bl[(wc + tj * 16 + l16) * LDSA_STRIDE + g * 8];
#pragma unroll
        for (int ti = 0; ti < 4; ++ti)
#pragma unroll
            for (int tj = 0; tj < 4; ++tj)
                acc[ti][tj] = __builtin_amdgcn_mfma_f32_16x16x32_f16(
                    af[ti], bfr[tj], acc[ti][tj], 0, 0, 0);
    }

#pragma unroll
    for (int tj = 0; tj < 4; ++tj) {
        int col = n0 + wc + tj * 16 + l16;
        if (col >= N) continue;
        float bv = bias ? bias[col] : 0.f;
#pragma unroll
        for (int ti = 0; ti < 4; ++ti) {
            int rbase = m0 + wr + ti * 16 + g * 4;
#pragma unroll
            for (int r = 0; r < 4; ++r) {
                float v = acc[ti][tj][r] + bv;
                if (relu) v = fmaxf(v, 0.f);
                C[(size_t)(rbase + r) * N + col] = v;
            }
        }
    }
}

// ---------------------------------------------------------------------------
// causal depthwise conv1d (k=4) + SiLU over xBC channels of zxbcdt
// ---------------------------------------------------------------------------
__global__ void conv_silu_kernel(const float* __restrict__ zxbcdt,
                                 const float* __restrict__ cw,
                                 const float* __restrict__ cb,
                                 float* __restrict__ xBCc)
{
    int idx = blockIdx.x * 256 + threadIdx.x;
    if (idx >= NTOK * CONV_DIM) return;
    int c  = idx % CONV_DIM;
    int bl = idx / CONV_DIM;
    int b  = bl >> 9;
    int l  = bl & 511;
    float acc = cb[c];
#pragma unroll
    for (int k = 0; k < DCONV; ++k) {
        int ll = l + k - (DCONV - 1);
        if (ll >= 0)
            acc = fmaf(zxbcdt[(size_t)(b * SEQ + ll) * D_IN_PROJ + D_INNER + c],
                       cw[c * DCONV + k], acc);
    }
    xBCc[idx] = acc / (1.f + expf(-acc));
}

// ---------------------------------------------------------------------------
// chunked selective scan: 1 block per (b,h), 512 threads.
// ---------------------------------------------------------------------------
#define SCHUNK 32
#define BUF_STRIDE 324
__global__ __launch_bounds__(512)
void scan_kernel(const float* __restrict__ zx, const float* __restrict__ xc,
                 const float* __restrict__ dt_bias, const float* __restrict__ A_log,
                 const float* __restrict__ D_skip, float* __restrict__ y)
{
    __shared__ __attribute__((aligned(16))) float buf[SCHUNK][BUF_STRIDE];
    __shared__ float dtv_s[SCHUNK], dA_s[SCHUNK];
    const int bh = blockIdx.x, b = bh >> 5, h = bh & 31;
    const int t = threadIdx.x, p = t >> 3, ng = t & 7;
    const float dtb = dt_bias[h];
    const float Acoef = -expf(A_log[h]);
    const float Dsk = D_skip[h];
    float s[16];
#pragma unroll
    for (int j = 0; j < 16; ++j) s[j] = 0.f;

    for (int c0 = 0; c0 < SEQ; c0 += SCHUNK) {
        __syncthreads();
        for (int idx = t; idx < SCHUNK * 320; idx += 512) {
            int sl = idx / 320, c = idx - sl * 320;
            const float* xr = xc + (size_t)(b * SEQ + c0 + sl) * CONV_DIM;
            float v;
            if (c < 64)       v = xr[h * 64 + c];
            else if (c < 192) v = xr[D_INNER + (c - 64)];
            else              v = xr[D_INNER + D_STATE + (c - 192)];
            buf[sl][c] = v;
        }
        if (t < SCHUNK) {
            int row = b * SEQ + c0 + t;
            float dtraw = zx[(size_t)row * D_IN_PROJ + (D_IN_PROJ - NHEADS) + h] + dtb;
            float dtv = (dtraw > 20.f) ? dtraw : log1pf(expf(dtraw));
            dtv_s[t] = dtv;
            dA_s[t] = expf(dtv * Acoef);
        }
        __syncthreads();
        for (int sl = 0; sl < SCHUNK; ++sl) {
            float dA = dA_s[sl], dtv = dtv_s[sl];
            float xv = buf[sl][p];
            float xp = xv * dtv;
            float yp = 0.f;
#pragma unroll
            for (int q = 0; q < 4; ++q) {
                float4 Bv = *(const float4*)&buf[sl][64  + ng * 4 + q * 32];
                float4 Cv = *(const float4*)&buf[sl][192 + ng * 4 + q * 32];
                s[q*4+0] = fmaf(s[q*4+0], dA, xp * Bv.x); yp = fmaf(s[q*4+0], Cv.x, yp);
                s[q*4+1] = fmaf(s[q*4+1], dA, xp * Bv.y); yp = fmaf(s[q*4+1], Cv.y, yp);
                s[q*4+2] = fmaf(s[q*4+2], dA, xp * Bv.z); yp = fmaf(s[q*4+2], Cv.z, yp);
                s[q*4+3] = fmaf(s[q*4+3], dA, xp * Bv.w); yp = fmaf(s[q*4+3], Cv.w, yp);
            }
            yp += __shfl_down(yp, 4, 8);
            yp += __shfl_down(yp, 2, 8);
            yp += __shfl_down(yp, 1, 8);
            if (ng == 0)
                y[(size_t)(b * SEQ + c0 + sl) * D_INNER + h * 64 + p] = yp + Dsk * xv;
        }
    }
}

// ---------------------------------------------------------------------------
// gated RMSNorm
// ---------------------------------------------------------------------------
__global__ __launch_bounds__(256)
void gated_rmsnorm_kernel(const float* __restrict__ y,
                          const float* __restrict__ zxbcdt,
                          const float* __restrict__ norm_w,
                          float* __restrict__ yn)
{
    int bl = blockIdx.x;
    int t  = threadIdx.x;
    const float* yr = y + (size_t)bl * D_INNER;
    const float* zr = zxbcdt + (size_t)bl * D_IN_PROJ;
    float* outr = yn + (size_t)bl * D_INNER;

    float gv[8];
    float ss = 0.f;
#pragma unroll
    for (int q = 0; q < 8; ++q) {
        int j = t + q * 256;
        float z = zr[j];
        float g = yr[j] * (z / (1.f + expf(-z)));
        gv[q] = g;
        ss += g * g;
    }
    __shared__ float red[256];
    red[t] = ss;
    __syncthreads();
    for (int w = 128; w > 0; w >>= 1) {
        if (t < w) red[t] += red[t + w];
        __syncthreads();
    }
    float rs = rsqrtf(red[0] / (float)D_INNER + 1e-5f);
#pragma unroll
    for (int q = 0; q < 8; ++q) {
        int j = t + q * 256;
        outr[j] = gv[q] * rs * norm_w[j];
    }
}

// ---------------------------------------------------------------------------
// final: out[tok] = dot(t1[tok,:], w2[:,0]) + b2
// ---------------------------------------------------------------------------
__global__ __launch_bounds__(256)
void final_dot_kernel(const float* __restrict__ t1,
                      const float* __restrict__ w2,
                      const float* __restrict__ b2,
                      float* __restrict__ out)
{
    int bl = blockIdx.x;
    int t  = threadIdx.x;
    float s = 0.f;
    for (int j = t; j < D_MODEL; j += 256)
        s = fmaf(t1[(size_t)bl * D_MODEL + j], w2[j], s);
    __shared__ float red[256];
    red[t] = s;
    __syncthreads();
    for (int w = 128; w > 0; w >>= 1) {
        if (t < w) red[t] += red[t + w];
        __syncthreads();
    }
    if (t == 0) out[bl] = red[0] + b2[0];
}

// ---------------------------------------------------------------------------
extern "C" void kernel_launch(void* const* d_in, const int* in_sizes, int n_in,
                              void* d_out, int out_size, void* d_ws, size_t ws_size,
                              hipStream_t stream)
{
    const float* x        = (const float*)d_in[0];
    const float* steps    = (const float*)d_in[1];
    const float* curr     = (const float*)d_in[2];
    const float* mi_w1    = (const float*)d_in[3];
    const float* mi_b1    = (const float*)d_in[4];
    const float* mi_w2    = (const float*)d_in[5];
    const float* mi_b2    = (const float*)d_in[6];
    const float* W_in     = (const float*)d_in[7];
    const float* conv_w   = (const float*)d_in[8];
    const float* conv_b   = (const float*)d_in[9];
    const float* dt_bias  = (const float*)d_in[10];
    const float* A_log    = (const float*)d_in[11];
    const float* D_skip   = (const float*)d_in[12];
    const float* norm_w   = (const float*)d_in[13];
    const float* W_out    = (const float*)d_in[14];
    const float* mo_w1    = (const float*)d_in[15];
    const float* mo_b1    = (const float*)d_in[16];
    const float* mo_w2    = (const float*)d_in[17];
    const float* mo_b2    = (const float*)d_in[18];
    float* out = (float*)d_out;

    // ---- workspace layout ----
    unsigned short* wt_mi1 = (unsigned short*)d_ws;                    // [512][512]
    unsigned short* wt_mi2 = wt_mi1 + (size_t)512 * 512;               // [1024][512]
    unsigned short* wt_in  = wt_mi2 + (size_t)1024 * 512;              // 4 x [4480][1024]
    unsigned short* wt_out = wt_in  + (size_t)4 * NPAD_IN * 1024;      // 4 x [1024][2048]
    unsigned short* wt_mo1 = wt_out + (size_t)4 * 1024 * 2048;         // [1024][1024]
    float* fbase = (float*)((((uintptr_t)(wt_mo1 + (size_t)1024 * 1024)) + 255) & ~(uintptr_t)255);

    float* hcat = fbase;                            // 2048*512
    float* t0   = hcat + (size_t)NTOK * 512;        // 2048*512
    float* h    = t0   + (size_t)NTOK * 512;        // 2048*1024
    float* zxb  = h    + (size_t)NTOK * D_MODEL;    // 2048*4384
    float* xc   = zxb  + (size_t)NTOK * D_IN_PROJ;  // 2048*2304
    float* yb   = xc   + (size_t)NTOK * CONV_DIM;   // 2048*2048
    float* yn   = yb   + (size_t)NTOK * D_INNER;    // 2048*2048
    float* t1   = hcat;                             // reuse 8 MB for [2048,1024]

    // ---- weight transposes (fp16) ----
    transpose_f16_kernel<<<dim3(512/32, 512/32), 256, 0, stream>>>(mi_w1, wt_mi1, 512, 512);
    transpose_f16_kernel<<<dim3(1024/32, 512/32), 256, 0, stream>>>(mi_w2, wt_mi2, 512, 1024);
    for (int i = 0; i < NBLOCKS; ++i) {
        transpose_f16_kernel<<<dim3(NPAD_IN/32, 1024/32), 256, 0, stream>>>(
            W_in + (size_t)i * D_MODEL * D_IN_PROJ, wt_in + (size_t)i * NPAD_IN * 1024,
            D_MODEL, D_IN_PROJ);
        transpose_f16_kernel<<<dim3(1024/32, 2048/32), 256, 0, stream>>>(
            W_out + (size_t)i * D_INNER * D_MODEL, wt_out + (size_t)i * 1024 * 2048,
            D_INNER, D_MODEL);
    }
    transpose_f16_kernel<<<dim3(1024/32, 1024/32), 256, 0, stream>>>(mo_w1, wt_mo1, 1024, 1024);

    // ---- forward ----
    concat_kernel<<<(NTOK * 512 + 255) / 256, 256, 0, stream>>>(x, steps, curr, hcat);

    mfma_gemm_kernel<<<dim3(512/128, NTOK/128), 256, 0, stream>>>(
        hcat, wt_mi1, mi_b1, t0, 512, 512, 1);
    mfma_gemm_kernel<<<dim3(1024/128, NTOK/128), 256, 0, stream>>>(
        t0, wt_mi2, mi_b2, h, 1024, 512, 0);

    for (int i = 0; i < NBLOCKS; ++i) {
        mfma_gemm_kernel<<<dim3((D_IN_PROJ + 127)/128, NTOK/128), 256, 0, stream>>>(
            h, wt_in + (size_t)i * NPAD_IN * 1024, nullptr, zxb, D_IN_PROJ, D_MODEL, 0);
        conv_silu_kernel<<<(NTOK * CONV_DIM + 255) / 256, 256, 0, stream>>>(
            zxb, conv_w + (size_t)i * CONV_DIM * DCONV, conv_b + (size_t)i * CONV_DIM, xc);
        scan_kernel<<<BATCH * NHEADS, 512, 0, stream>>>(
            zxb, xc, dt_bias + i * NHEADS, A_log + i * NHEADS, D_skip + i * NHEADS, yb);
        gated_rmsnorm_kernel<<<NTOK, 256, 0, stream>>>(
            yb, zxb, norm_w + (size_t)i * D_INNER, yn);
        mfma_gemm_kernel<<<dim3(1024/128, NTOK/128), 256, 0, stream>>>(
            yn, wt_out + (size_t)i * 1024 * 2048, nullptr, h, 1024, 2048, 0);
    }

    mfma_gemm_kernel<<<dim3(1024/128, NTOK/128), 256, 0, stream>>>(
        h, wt_mo1, mo_b1, t1, 1024, 1024, 1);
    final_dot_kernel<<<NTOK, 256, 0, stream>>>(t1, mo_w2, mo_b2, out);
}

// Round 4
// 1384.283 us; speedup vs baseline: 4.0434x; 1.2231x over previous
//
#include <hip/hip_runtime.h>
#include <hip/hip_bf16.h>
#include <math.h>

#define D_MODEL   1024
#define D_INNER   2048
#define D_STATE   128
#define NHEADS    32
#define HEADDIM   64
#define DCONV     4
#define CONV_DIM  (D_INNER + 2 * D_STATE)              // 2304
#define D_IN_PROJ (2 * D_INNER + 2 * D_STATE + NHEADS) // 4384
#define NBLOCKS   4
#define BATCH     4
#define SEQ       512
#define NTOK      (BATCH * SEQ)                        // 2048
#define STATE_IN  510
#define NPAD_IN   4480                                 // D_IN_PROJ padded to 128
#define NSEG      8
#define SEGLEN    64                                   // SEQ / NSEG
#define NBH       (BATCH * NHEADS)                     // 128

typedef _Float16 half8_t __attribute__((ext_vector_type(8)));
typedef float f32x4_t  __attribute__((ext_vector_type(4)));

__device__ __forceinline__ unsigned short f2h(float f) {
    _Float16 h = (_Float16)f;
    return __builtin_bit_cast(unsigned short, h);
}
__device__ __forceinline__ float h2f(unsigned short u) {
    return (float)__builtin_bit_cast(_Float16, u);
}

// ---------------------------------------------------------------------------
// concat [x, steps_left, current_r] -> hcat [NTOK, 512]
// ---------------------------------------------------------------------------
__global__ void concat_kernel(const float* __restrict__ x,
                              const float* __restrict__ steps,
                              const float* __restrict__ curr,
                              float* __restrict__ hcat)
{
    int idx = blockIdx.x * 256 + threadIdx.x;
    if (idx >= NTOK * 512) return;
    int bl = idx >> 9;
    int c  = idx & 511;
    float v;
    if (c < STATE_IN)       v = x[(size_t)bl * STATE_IN + c];
    else if (c == STATE_IN) v = steps[bl];
    else                    v = curr[bl];
    hcat[idx] = v;
}

// ---------------------------------------------------------------------------
// weight transpose + fp16 convert:  W[K,N] fp32 -> WT[Npad,K] fp16
// ---------------------------------------------------------------------------
__global__ __launch_bounds__(256)
void transpose_f16_kernel(const float* __restrict__ W, unsigned short* __restrict__ WT,
                          int K, int N)
{
    __shared__ unsigned short tile[32][36];
    int n0 = blockIdx.x * 32, k0 = blockIdx.y * 32;
    int t = threadIdx.x;
    int kl = t >> 3, nl = (t & 7) * 4;
    float4 v = make_float4(0.f, 0.f, 0.f, 0.f);
    if (n0 < N) v = *(const float4*)(W + (size_t)(k0 + kl) * N + n0 + nl);
    tile[nl + 0][kl] = f2h(v.x);
    tile[nl + 1][kl] = f2h(v.y);
    tile[nl + 2][kl] = f2h(v.z);
    tile[nl + 3][kl] = f2h(v.w);
    __syncthreads();
    int nl2 = t >> 3, kl2 = (t & 7) * 4;
    ushort4 o;
    o.x = tile[nl2][kl2 + 0];
    o.y = tile[nl2][kl2 + 1];
    o.z = tile[nl2][kl2 + 2];
    o.w = tile[nl2][kl2 + 3];
    *(ushort4*)(WT + (size_t)(n0 + nl2) * K + k0 + kl2) = o;
}

// ---------------------------------------------------------------------------
// fp16 MFMA GEMM (unchanged from round 3)
// ---------------------------------------------------------------------------
#define LDSA_STRIDE 40
__global__ __launch_bounds__(256)
void mfma_gemm_kernel(const float* __restrict__ A, const unsigned short* __restrict__ BT,
                      const float* __restrict__ bias, float* __restrict__ C,
                      int N, int K, int relu)
{
    __shared__ unsigned short Al[128 * LDSA_STRIDE];
    __shared__ unsigned short Bl[128 * LDSA_STRIDE];
    const int tid  = threadIdx.x;
    const int lane = tid & 63;
    const int wave = tid >> 6;
    const int wr   = (wave >> 1) * 64, wc = (wave & 1) * 64;
    const int g    = lane >> 4, l16 = lane & 15;
    const int m0   = blockIdx.y * 128, n0 = blockIdx.x * 128;
    const int arow = tid >> 1;
    const int ak   = (tid & 1) * 16;

    f32x4_t acc[4][4];
    const f32x4_t zero = {0.f, 0.f, 0.f, 0.f};
#pragma unroll
    for (int i = 0; i < 4; ++i)
#pragma unroll
        for (int j = 0; j < 4; ++j) acc[i][j] = zero;

    const float*          aptr = A  + (size_t)(m0 + arow) * K + ak;
    const unsigned short* bptr = BT + (size_t)(n0 + arow) * K + ak;
    unsigned short* adst = &Al[arow * LDSA_STRIDE + ak];
    unsigned short* bdst = &Bl[arow * LDSA_STRIDE + ak];

    for (int k0 = 0; k0 < K; k0 += 32) {
        float4 v0 = *(const float4*)(aptr + k0);
        float4 v1 = *(const float4*)(aptr + k0 + 4);
        float4 v2 = *(const float4*)(aptr + k0 + 8);
        float4 v3 = *(const float4*)(aptr + k0 + 12);
        uint4  b0 = *(const uint4*)(bptr + k0);
        uint4  b1 = *(const uint4*)(bptr + k0 + 8);
        __syncthreads();
        unsigned int p0 = f2h(v0.x) | ((unsigned int)f2h(v0.y) << 16);
        unsigned int p1 = f2h(v0.z) | ((unsigned int)f2h(v0.w) << 16);
        unsigned int p2 = f2h(v1.x) | ((unsigned int)f2h(v1.y) << 16);
        unsigned int p3 = f2h(v1.z) | ((unsigned int)f2h(v1.w) << 16);
        unsigned int p4 = f2h(v2.x) | ((unsigned int)f2h(v2.y) << 16);
        unsigned int p5 = f2h(v2.z) | ((unsigned int)f2h(v2.w) << 16);
        unsigned int p6 = f2h(v3.x) | ((unsigned int)f2h(v3.y) << 16);
        unsigned int p7 = f2h(v3.z) | ((unsigned int)f2h(v3.w) << 16);
        ((uint4*)adst)[0] = make_uint4(p0, p1, p2, p3);
        ((uint4*)adst)[1] = make_uint4(p4, p5, p6, p7);
        ((uint4*)bdst)[0] = b0;
        ((uint4*)bdst)[1] = b1;
        __syncthreads();
        half8_t af[4], bfr[4];
#pragma unroll
        for (int ti = 0; ti < 4; ++ti)
            af[ti] = *(const half8_t*)&Al[(wr + ti * 16 + l16) * LDSA_STRIDE + g * 8];
#pragma unroll
        for (int tj = 0; tj < 4; ++tj)
            bfr[tj] = *(const half8_t*)&Bl[(wc + tj * 16 + l16) * LDSA_STRIDE + g * 8];
#pragma unroll
        for (int ti = 0; ti < 4; ++ti)
#pragma unroll
            for (int tj = 0; tj < 4; ++tj)
                acc[ti][tj] = __builtin_amdgcn_mfma_f32_16x16x32_f16(
                    af[ti], bfr[tj], acc[ti][tj], 0, 0, 0);
    }

#pragma unroll
    for (int tj = 0; tj < 4; ++tj) {
        int col = n0 + wc + tj * 16 + l16;
        if (col >= N) continue;
        float bv = bias ? bias[col] : 0.f;
#pragma unroll
        for (int ti = 0; ti < 4; ++ti) {
            int rbase = m0 + wr + ti * 16 + g * 4;
#pragma unroll
            for (int r = 0; r < 4; ++r) {
                float v = acc[ti][tj][r] + bv;
                if (relu) v = fmaxf(v, 0.f);
                C[(size_t)(rbase + r) * N + col] = v;
            }
        }
    }
}

// ---------------------------------------------------------------------------
// causal depthwise conv1d (k=4) + SiLU
// ---------------------------------------------------------------------------
__global__ void conv_silu_kernel(const float* __restrict__ zxbcdt,
                                 const float* __restrict__ cw,
                                 const float* __restrict__ cb,
                                 float* __restrict__ xBCc)
{
    int idx = blockIdx.x * 256 + threadIdx.x;
    if (idx >= NTOK * CONV_DIM) return;
    int c  = idx % CONV_DIM;
    int bl = idx / CONV_DIM;
    int b  = bl >> 9;
    int l  = bl & 511;
    float acc = cb[c];
#pragma unroll
    for (int k = 0; k < DCONV; ++k) {
        int ll = l + k - (DCONV - 1);
        if (ll >= 0)
            acc = fmaf(zxbcdt[(size_t)(b * SEQ + ll) * D_IN_PROJ + D_INNER + c],
                       cw[c * DCONV + k], acc);
    }
    xBCc[idx] = acc / (1.f + expf(-acc));
}

// ---------------------------------------------------------------------------
// PASS 1: segmented local scan. 1 block per (b,h,seg); 512 threads.
// Scans SEGLEN steps from zero state; writes y_local (+D skip), per-step
// cumulative decay alpha, and final state Hseg (fp16).
// thread t: p = t>>3, owns states n = (t&7)*4 + q*32 + r.
// ---------------------------------------------------------------------------
#define SCHUNK 16
#define BUF_STRIDE 324
__global__ __launch_bounds__(512)
void scan_seg_kernel(const float* __restrict__ zx, const float* __restrict__ xc,
                     const float* __restrict__ dt_bias, const float* __restrict__ A_log,
                     const float* __restrict__ D_skip, float* __restrict__ y,
                     float* __restrict__ alpha, unsigned short* __restrict__ Hseg)
{
    __shared__ __attribute__((aligned(16))) float buf[SCHUNK][BUF_STRIDE];
    __shared__ float dtv_s[SCHUNK], dA_s[SCHUNK], acs[SCHUNK];
    __shared__ float carry_s;
    const int bi = blockIdx.x;
    const int bh = bi >> 3, seg = bi & 7;
    const int b = bh >> 5, h = bh & 31;
    const int t = threadIdx.x, p = t >> 3, ng = t & 7;
    const int t0g = seg * SEGLEN;
    const float dtb = dt_bias[h];
    const float Acoef = -expf(A_log[h]);
    const float Dsk = D_skip[h];
    if (t == 0) carry_s = 1.f;
    float s[16];
#pragma unroll
    for (int j = 0; j < 16; ++j) s[j] = 0.f;

    for (int c0 = 0; c0 < SEGLEN; c0 += SCHUNK) {
        __syncthreads();
        for (int idx = t; idx < SCHUNK * 320; idx += 512) {
            int sl = idx / 320, c = idx - sl * 320;
            const float* xr = xc + (size_t)(b * SEQ + t0g + c0 + sl) * CONV_DIM;
            float v;
            if (c < 64)       v = xr[h * 64 + c];
            else if (c < 192) v = xr[D_INNER + (c - 64)];
            else              v = xr[D_INNER + D_STATE + (c - 192)];
            buf[sl][c] = v;
        }
        if (t < SCHUNK) {
            int row = b * SEQ + t0g + c0 + t;
            float dtraw = zx[(size_t)row * D_IN_PROJ + (D_IN_PROJ - NHEADS) + h] + dtb;
            float dtv = (dtraw > 20.f) ? dtraw : log1pf(expf(dtraw));
            dtv_s[t] = dtv;
            dA_s[t] = expf(dtv * Acoef);
        }
        __syncthreads();
        if (t == 0) {
            float ac = carry_s;
#pragma unroll
            for (int i = 0; i < SCHUNK; ++i) { ac *= dA_s[i]; acs[i] = ac; }
            carry_s = ac;
        }
        __syncthreads();
        if (t < SCHUNK)
            alpha[(size_t)bh * SEQ + t0g + c0 + t] = acs[t];
        for (int sl = 0; sl < SCHUNK; ++sl) {
            float dA = dA_s[sl], dtv = dtv_s[sl];
            float xv = buf[sl][p];
            float xp = xv * dtv;
            float yp = 0.f;
#pragma unroll
            for (int q = 0; q < 4; ++q) {
                float4 Bv = *(const float4*)&buf[sl][64  + ng * 4 + q * 32];
                float4 Cv = *(const float4*)&buf[sl][192 + ng * 4 + q * 32];
                s[q*4+0] = fmaf(s[q*4+0], dA, xp * Bv.x); yp = fmaf(s[q*4+0], Cv.x, yp);
                s[q*4+1] = fmaf(s[q*4+1], dA, xp * Bv.y); yp = fmaf(s[q*4+1], Cv.y, yp);
                s[q*4+2] = fmaf(s[q*4+2], dA, xp * Bv.z); yp = fmaf(s[q*4+2], Cv.z, yp);
                s[q*4+3] = fmaf(s[q*4+3], dA, xp * Bv.w); yp = fmaf(s[q*4+3], Cv.w, yp);
            }
            yp += __shfl_down(yp, 4, 8);
            yp += __shfl_down(yp, 2, 8);
            yp += __shfl_down(yp, 1, 8);
            if (ng == 0)
                y[(size_t)(b * SEQ + t0g + c0 + sl) * D_INNER + h * 64 + p] = yp + Dsk * xv;
        }
    }
    // store final state fp16: Hseg[bi][p][n]
    unsigned short* hs = Hseg + ((size_t)bi * 64 + p) * 128;
#pragma unroll
    for (int q = 0; q < 4; ++q) {
        ushort4 o;
        o.x = f2h(s[q*4+0]); o.y = f2h(s[q*4+1]);
        o.z = f2h(s[q*4+2]); o.w = f2h(s[q*4+3]);
        *(ushort4*)(hs + ng * 4 + q * 32) = o;
    }
}

// ---------------------------------------------------------------------------
// PASS 2: sequential fixup across segments (in-place: Hseg -> Hin).
// 1 block per (b,h); 512 threads; each thread owns its 16 state elements.
// ---------------------------------------------------------------------------
__global__ __launch_bounds__(512)
void state_fixup_kernel(const float* __restrict__ alpha, unsigned short* __restrict__ Hseg)
{
    const int bh = blockIdx.x;
    const int t = threadIdx.x, p = t >> 3, ng = t & 7;
    float carry[16];
#pragma unroll
    for (int j = 0; j < 16; ++j) carry[j] = 0.f;
    for (int seg = 0; seg < NSEG; ++seg) {
        unsigned short* hs = Hseg + (((size_t)bh * NSEG + seg) * 64 + p) * 128;
        float ae = alpha[(size_t)bh * SEQ + seg * SEGLEN + SEGLEN - 1];
        float tmp[16];
#pragma unroll
        for (int q = 0; q < 4; ++q) {
            ushort4 u = *(const ushort4*)(hs + ng * 4 + q * 32);
            tmp[q*4+0] = h2f(u.x); tmp[q*4+1] = h2f(u.y);
            tmp[q*4+2] = h2f(u.z); tmp[q*4+3] = h2f(u.w);
        }
#pragma unroll
        for (int q = 0; q < 4; ++q) {
            ushort4 o;
            o.x = f2h(carry[q*4+0]); o.y = f2h(carry[q*4+1]);
            o.z = f2h(carry[q*4+2]); o.w = f2h(carry[q*4+3]);
            *(ushort4*)(hs + ng * 4 + q * 32) = o;   // Hin for this segment
        }
#pragma unroll
        for (int j = 0; j < 16; ++j) carry[j] = fmaf(carry[j], ae, tmp[j]);
    }
}

// ---------------------------------------------------------------------------
// PASS 3: y_t += alpha_t * (C_t . Hin_seg).  Segments 1..7 only.
// 1 block per (b,h,seg-1); 512 threads.
// ---------------------------------------------------------------------------
__global__ __launch_bounds__(512)
void correct_kernel(const float* __restrict__ xc, const float* __restrict__ alpha,
                    const unsigned short* __restrict__ Hseg, float* __restrict__ y)
{
    __shared__ __attribute__((aligned(16))) float Csh[SCHUNK][132];
    __shared__ float ac_sh[SCHUNK];
    const int bi = blockIdx.x;
    const int bh = bi / 7, seg = 1 + (bi % 7);
    const int b = bh >> 5, h = bh & 31;
    const int t = threadIdx.x, p = t >> 3, ng = t & 7;
    const int t0g = seg * SEGLEN;

    float s[16];
    const unsigned short* hs = Hseg + (((size_t)bh * NSEG + seg) * 64 + p) * 128;
#pragma unroll
    for (int q = 0; q < 4; ++q) {
        ushort4 u = *(const ushort4*)(hs + ng * 4 + q * 32);
        s[q*4+0] = h2f(u.x); s[q*4+1] = h2f(u.y);
        s[q*4+2] = h2f(u.z); s[q*4+3] = h2f(u.w);
    }

    for (int c0 = 0; c0 < SEGLEN; c0 += SCHUNK) {
        __syncthreads();
        for (int idx = t; idx < SCHUNK * 128; idx += 512) {
            int sl = idx >> 7, c = idx & 127;
            Csh[sl][c] = xc[(size_t)(b * SEQ + t0g + c0 + sl) * CONV_DIM
                            + D_INNER + D_STATE + c];
        }
        if (t < SCHUNK)
            ac_sh[t] = alpha[(size_t)bh * SEQ + t0g + c0 + t];
        __syncthreads();
        for (int sl = 0; sl < SCHUNK; ++sl) {
            float yp = 0.f;
#pragma unroll
            for (int q = 0; q < 4; ++q) {
                float4 Cv = *(const float4*)&Csh[sl][ng * 4 + q * 32];
                yp = fmaf(s[q*4+0], Cv.x, yp);
                yp = fmaf(s[q*4+1], Cv.y, yp);
                yp = fmaf(s[q*4+2], Cv.z, yp);
                yp = fmaf(s[q*4+3], Cv.w, yp);
            }
            yp += __shfl_down(yp, 4, 8);
            yp += __shfl_down(yp, 2, 8);
            yp += __shfl_down(yp, 1, 8);
            if (ng == 0) {
                size_t idx = (size_t)(b * SEQ + t0g + c0 + sl) * D_INNER + h * 64 + p;
                y[idx] += ac_sh[sl] * yp;
            }
        }
    }
}

// ---------------------------------------------------------------------------
// gated RMSNorm (in-place capable: out may alias y)
// ---------------------------------------------------------------------------
__global__ __launch_bounds__(256)
void gated_rmsnorm_kernel(const float* __restrict__ y,
                          const float* __restrict__ zxbcdt,
                          const float* __restrict__ norm_w,
                          float* __restrict__ yn)
{
    int bl = blockIdx.x;
    int t  = threadIdx.x;
    const float* yr = y + (size_t)bl * D_INNER;
    const float* zr = zxbcdt + (size_t)bl * D_IN_PROJ;
    float* outr = yn + (size_t)bl * D_INNER;

    float gv[8];
    float ss = 0.f;
#pragma unroll
    for (int q = 0; q < 8; ++q) {
        int j = t + q * 256;
        float z = zr[j];
        float g = yr[j] * (z / (1.f + expf(-z)));
        gv[q] = g;
        ss += g * g;
    }
    __shared__ float red[256];
    red[t] = ss;
    __syncthreads();
    for (int w = 128; w > 0; w >>= 1) {
        if (t < w) red[t] += red[t + w];
        __syncthreads();
    }
    float rs = rsqrtf(red[0] / (float)D_INNER + 1e-5f);
#pragma unroll
    for (int q = 0; q < 8; ++q) {
        int j = t + q * 256;
        outr[j] = gv[q] * rs * norm_w[j];
    }
}

// ---------------------------------------------------------------------------
// final: out[tok] = dot(t1[tok,:], w2[:,0]) + b2
// ---------------------------------------------------------------------------
__global__ __launch_bounds__(256)
void final_dot_kernel(const float* __restrict__ t1,
                      const float* __restrict__ w2,
                      const float* __restrict__ b2,
                      float* __restrict__ out)
{
    int bl = blockIdx.x;
    int t  = threadIdx.x;
    float s = 0.f;
    for (int j = t; j < D_MODEL; j += 256)
        s = fmaf(t1[(size_t)bl * D_MODEL + j], w2[j], s);
    __shared__ float red[256];
    red[t] = s;
    __syncthreads();
    for (int w = 128; w > 0; w >>= 1) {
        if (t < w) red[t] += red[t + w];
        __syncthreads();
    }
    if (t == 0) out[bl] = red[0] + b2[0];
}

// ---------------------------------------------------------------------------
extern "C" void kernel_launch(void* const* d_in, const int* in_sizes, int n_in,
                              void* d_out, int out_size, void* d_ws, size_t ws_size,
                              hipStream_t stream)
{
    const float* x        = (const float*)d_in[0];
    const float* steps    = (const float*)d_in[1];
    const float* curr     = (const float*)d_in[2];
    const float* mi_w1    = (const float*)d_in[3];
    const float* mi_b1    = (const float*)d_in[4];
    const float* mi_w2    = (const float*)d_in[5];
    const float* mi_b2    = (const float*)d_in[6];
    const float* W_in     = (const float*)d_in[7];
    const float* conv_w   = (const float*)d_in[8];
    const float* conv_b   = (const float*)d_in[9];
    const float* dt_bias  = (const float*)d_in[10];
    const float* A_log    = (const float*)d_in[11];
    const float* D_skip   = (const float*)d_in[12];
    const float* norm_w   = (const float*)d_in[13];
    const float* W_out    = (const float*)d_in[14];
    const float* mo_w1    = (const float*)d_in[15];
    const float* mo_b1    = (const float*)d_in[16];
    const float* mo_w2    = (const float*)d_in[17];
    const float* mo_b2    = (const float*)d_in[18];
    float* out = (float*)d_out;

    // ---- workspace layout ----
    unsigned short* wt_mi1 = (unsigned short*)d_ws;                    // [512][512]
    unsigned short* wt_mi2 = wt_mi1 + (size_t)512 * 512;               // [1024][512]
    unsigned short* wt_in  = wt_mi2 + (size_t)1024 * 512;              // 4 x [4480][1024]
    unsigned short* wt_out = wt_in  + (size_t)4 * NPAD_IN * 1024;      // 4 x [1024][2048]
    unsigned short* wt_mo1 = wt_out + (size_t)4 * 1024 * 2048;         // [1024][1024]
    unsigned short* Hseg   = wt_mo1 + (size_t)1024 * 1024;             // 128*8*64*128 fp16
    float* fbase = (float*)((((uintptr_t)(Hseg + (size_t)NBH * NSEG * 64 * 128)) + 255)
                            & ~(uintptr_t)255);

    float* hcat  = fbase;                            // 2048*512
    float* h     = hcat  + (size_t)NTOK * 512;       // 2048*1024
    float* zxb   = h     + (size_t)NTOK * D_MODEL;   // 2048*4384
    float* xc    = zxb   + (size_t)NTOK * D_IN_PROJ; // 2048*2304
    float* yb    = xc    + (size_t)NTOK * CONV_DIM;  // 2048*2048  (yn aliases)
    float* alpha = yb    + (size_t)NTOK * D_INNER;   // 128*512
    float* t0    = zxb;                              // alias: zxb unused until block 0
    float* yn    = yb;                               // in-place rmsnorm
    float* t1    = hcat;                             // reuse at end

    // ---- weight transposes (fp16) ----
    transpose_f16_kernel<<<dim3(512/32, 512/32), 256, 0, stream>>>(mi_w1, wt_mi1, 512, 512);
    transpose_f16_kernel<<<dim3(1024/32, 512/32), 256, 0, stream>>>(mi_w2, wt_mi2, 512, 1024);
    for (int i = 0; i < NBLOCKS; ++i) {
        transpose_f16_kernel<<<dim3(NPAD_IN/32, 1024/32), 256, 0, stream>>>(
            W_in + (size_t)i * D_MODEL * D_IN_PROJ, wt_in + (size_t)i * NPAD_IN * 1024,
            D_MODEL, D_IN_PROJ);
        transpose_f16_kernel<<<dim3(1024/32, 2048/32), 256, 0, stream>>>(
            W_out + (size_t)i * D_INNER * D_MODEL, wt_out + (size_t)i * 1024 * 2048,
            D_INNER, D_MODEL);
    }
    transpose_f16_kernel<<<dim3(1024/32, 1024/32), 256, 0, stream>>>(mo_w1, wt_mo1, 1024, 1024);

    // ---- forward ----
    concat_kernel<<<(NTOK * 512 + 255) / 256, 256, 0, stream>>>(x, steps, curr, hcat);

    mfma_gemm_kernel<<<dim3(512/128, NTOK/128), 256, 0, stream>>>(
        hcat, wt_mi1, mi_b1, t0, 512, 512, 1);
    mfma_gemm_kernel<<<dim3(1024/128, NTOK/128), 256, 0, stream>>>(
        t0, wt_mi2, mi_b2, h, 1024, 512, 0);

    for (int i = 0; i < NBLOCKS; ++i) {
        mfma_gemm_kernel<<<dim3((D_IN_PROJ + 127)/128, NTOK/128), 256, 0, stream>>>(
            h, wt_in + (size_t)i * NPAD_IN * 1024, nullptr, zxb, D_IN_PROJ, D_MODEL, 0);
        conv_silu_kernel<<<(NTOK * CONV_DIM + 255) / 256, 256, 0, stream>>>(
            zxb, conv_w + (size_t)i * CONV_DIM * DCONV, conv_b + (size_t)i * CONV_DIM, xc);
        scan_seg_kernel<<<NBH * NSEG, 512, 0, stream>>>(
            zxb, xc, dt_bias + i * NHEADS, A_log + i * NHEADS, D_skip + i * NHEADS,
            yb, alpha, Hseg);
        state_fixup_kernel<<<NBH, 512, 0, stream>>>(alpha, Hseg);
        correct_kernel<<<NBH * (NSEG - 1), 512, 0, stream>>>(xc, alpha, Hseg, yb);
        gated_rmsnorm_kernel<<<NTOK, 256, 0, stream>>>(
            yb, zxb, norm_w + (size_t)i * D_INNER, yn);
        mfma_gemm_kernel<<<dim3(1024/128, NTOK/128), 256, 0, stream>>>(
            yn, wt_out + (size_t)i * 1024 * 2048, nullptr, h, 1024, 2048, 0);
    }

    mfma_gemm_kernel<<<dim3(1024/128, NTOK/128), 256, 0, stream>>>(
        h, wt_mo1, mo_b1, t1, 1024, 1024, 1);
    final_dot_kernel<<<NTOK, 256, 0, stream>>>(t1, mo_w2, mo_b2, out);
}

// Round 5
// 1150.827 us; speedup vs baseline: 4.8636x; 1.2029x over previous
//
#include <hip/hip_runtime.h>
#include <hip/hip_bf16.h>
#include <math.h>

#define D_MODEL   1024
#define D_INNER   2048
#define D_STATE   128
#define NHEADS    32
#define HEADDIM   64
#define DCONV     4
#define CONV_DIM  (D_INNER + 2 * D_STATE)              // 2304
#define D_IN_PROJ (2 * D_INNER + 2 * D_STATE + NHEADS) // 4384
#define NBLOCKS   4
#define BATCH     4
#define SEQ       512
#define NTOK      (BATCH * SEQ)                        // 2048
#define STATE_IN  510
#define NPAD_IN   4480                                 // D_IN_PROJ padded to 128
#define NSEG      8
#define SEGLEN    64
#define NBH       (BATCH * NHEADS)                     // 128

typedef _Float16 half8_t __attribute__((ext_vector_type(8)));
typedef float f32x4_t  __attribute__((ext_vector_type(4)));
typedef unsigned short us;

__device__ __forceinline__ us f2h(float f) {
    _Float16 h = (_Float16)f;
    return __builtin_bit_cast(us, h);
}
__device__ __forceinline__ float h2f(us u) {
    return (float)__builtin_bit_cast(_Float16, u);
}
// async global->LDS, 16B per lane; lds dest must be wave-uniform base (lane i -> +i*16)
__device__ __forceinline__ void gl2lds16(const us* gp, us* lp) {
    __builtin_amdgcn_global_load_lds(
        (const __attribute__((address_space(1))) unsigned int*)(gp),
        (__attribute__((address_space(3))) unsigned int*)(lp), 16, 0, 0);
}

// ---------------------------------------------------------------------------
// concat [x, steps_left, current_r] -> hcat [NTOK, 512] fp16
// ---------------------------------------------------------------------------
__global__ void concat_kernel(const float* __restrict__ x,
                              const float* __restrict__ steps,
                              const float* __restrict__ curr,
                              us* __restrict__ hcat)
{
    int idx = blockIdx.x * 256 + threadIdx.x;
    if (idx >= NTOK * 512) return;
    int bl = idx >> 9;
    int c  = idx & 511;
    float v;
    if (c < STATE_IN)       v = x[(size_t)bl * STATE_IN + c];
    else if (c == STATE_IN) v = steps[bl];
    else                    v = curr[bl];
    hcat[idx] = f2h(v);
}

// ---------------------------------------------------------------------------
// weight transpose + fp16 convert:  W[K,N] fp32 -> WT[Npad,K] fp16
// ---------------------------------------------------------------------------
__global__ __launch_bounds__(256)
void transpose_f16_kernel(const float* __restrict__ W, us* __restrict__ WT,
                          int K, int N)
{
    __shared__ us tile[32][36];
    int n0 = blockIdx.x * 32, k0 = blockIdx.y * 32;
    int t = threadIdx.x;
    int kl = t >> 3, nl = (t & 7) * 4;
    float4 v = make_float4(0.f, 0.f, 0.f, 0.f);
    if (n0 < N) v = *(const float4*)(W + (size_t)(k0 + kl) * N + n0 + nl);
    tile[nl + 0][kl] = f2h(v.x);
    tile[nl + 1][kl] = f2h(v.y);
    tile[nl + 2][kl] = f2h(v.z);
    tile[nl + 3][kl] = f2h(v.w);
    __syncthreads();
    int nl2 = t >> 3, kl2 = (t & 7) * 4;
    ushort4 o;
    o.x = tile[nl2][kl2 + 0];
    o.y = tile[nl2][kl2 + 1];
    o.z = tile[nl2][kl2 + 2];
    o.w = tile[nl2][kl2 + 3];
    *(ushort4*)(WT + (size_t)(n0 + nl2) * K + k0 + kl2) = o;
}

// ---------------------------------------------------------------------------
// fp16 MFMA GEMM with async global->LDS staging (m97 structure).
// A fp16 [M,K]; BT fp16 [Npad,K]; C fp16 [M,N] = act(A@B + bias).
// 128xBN tile, BK=32, 256 threads. BN=128: waves 2x2 (TI=4). BN=64: waves
// 4x1 over M (TI=2). LDS tiles unpadded [rows][32]; bank aliasing broken by
// XOR column swizzle applied at fetch (block p holds logical block
// p ^ ((row>>2)&3)); readers apply the same XOR -> 2-way (free, m136).
// ---------------------------------------------------------------------------
template<int BN, int TI>
__global__ __launch_bounds__(256)
void mfma_gemm_f16(const us* __restrict__ A, const us* __restrict__ BT,
                   const float* __restrict__ bias, us* __restrict__ C,
                   int N, int K, int relu)
{
    __shared__ us Al[128 * 32];
    __shared__ us Bl[BN * 32];
    const int tid = threadIdx.x, lane = tid & 63, wave = tid >> 6;
    const int g = lane >> 4, l16 = lane & 15;
    const int wr = (BN == 128) ? (wave >> 1) * 64 : wave * 32;
    const int wc = (BN == 128) ? (wave & 1) * 64 : 0;
    const int m0 = blockIdx.y * 128, n0 = blockIdx.x * BN;
    const int lrow = lane >> 2;                         // 0..15 within an issue
    const int lcol = ((lane & 3) ^ ((lrow >> 2) & 3)) * 8;  // swizzled k-block

    f32x4_t acc[TI][4];
    const f32x4_t zero = {0.f, 0.f, 0.f, 0.f};
#pragma unroll
    for (int i = 0; i < TI; ++i)
#pragma unroll
        for (int j = 0; j < 4; ++j) acc[i][j] = zero;

    const us* abase = A  + (size_t)m0 * K;
    const us* bbase = BT + (size_t)n0 * K;

    for (int k0 = 0; k0 < K; k0 += 32) {
        __syncthreads();   // prior iter's frag reads done before overwrite
#pragma unroll
        for (int s = 0; s < 2; ++s) {
            int rb = wave * 32 + s * 16;
            gl2lds16(abase + (size_t)(rb + lrow) * K + k0 + lcol, &Al[rb * 32]);
        }
#pragma unroll
        for (int s = 0; s < BN / 64; ++s) {
            int rb = wave * (BN / 4) + s * 16;
            gl2lds16(bbase + (size_t)(rb + lrow) * K + k0 + lcol, &Bl[rb * 32]);
        }
        __syncthreads();   // vmcnt(0) drain + barrier: tiles resident
        half8_t af[TI], bfr[4];
#pragma unroll
        for (int ti = 0; ti < TI; ++ti) {
            int r = wr + ti * 16 + l16;
            af[ti] = *(const half8_t*)&Al[r * 32 + ((g ^ ((r >> 2) & 3)) * 8)];
        }
#pragma unroll
        for (int tj = 0; tj < 4; ++tj) {
            int r = wc + tj * 16 + l16;
            bfr[tj] = *(const half8_t*)&Bl[r * 32 + ((g ^ ((r >> 2) & 3)) * 8)];
        }
#pragma unroll
        for (int ti = 0; ti < TI; ++ti)
#pragma unroll
            for (int tj = 0; tj < 4; ++tj)
                acc[ti][tj] = __builtin_amdgcn_mfma_f32_16x16x32_f16(
                    af[ti], bfr[tj], acc[ti][tj], 0, 0, 0);
    }

#pragma unroll
    for (int tj = 0; tj < 4; ++tj) {
        int col = n0 + wc + tj * 16 + l16;
        if (col >= N) continue;
        float bv = bias ? bias[col] : 0.f;
#pragma unroll
        for (int ti = 0; ti < TI; ++ti) {
            int rbase = m0 + wr + ti * 16 + g * 4;
#pragma unroll
            for (int r = 0; r < 4; ++r) {
                float v = acc[ti][tj][r] + bv;
                if (relu) v = fmaxf(v, 0.f);
                C[(size_t)(rbase + r) * N + col] = f2h(v);
            }
        }
    }
}

// ---------------------------------------------------------------------------
// causal depthwise conv1d (k=4) + SiLU; fp16 in/out, fp32 math
// ---------------------------------------------------------------------------
__global__ void conv_silu_kernel(const us* __restrict__ zxbcdt,
                                 const float* __restrict__ cw,
                                 const float* __restrict__ cb,
                                 us* __restrict__ xBCc)
{
    int idx = blockIdx.x * 256 + threadIdx.x;
    if (idx >= NTOK * CONV_DIM) return;
    int c  = idx % CONV_DIM;
    int bl = idx / CONV_DIM;
    int b  = bl >> 9;
    int l  = bl & 511;
    float acc = cb[c];
#pragma unroll
    for (int k = 0; k < DCONV; ++k) {
        int ll = l + k - (DCONV - 1);
        if (ll >= 0)
            acc = fmaf(h2f(zxbcdt[(size_t)(b * SEQ + ll) * D_IN_PROJ + D_INNER + c]),
                       cw[c * DCONV + k], acc);
    }
    xBCc[idx] = f2h(acc / (1.f + expf(-acc)));
}

// ---------------------------------------------------------------------------
// PASS 1: segmented local scan (fp16 inputs, fp32 state/math)
// ---------------------------------------------------------------------------
#define SCHUNK 16
#define BUF_STRIDE 324
__global__ __launch_bounds__(512)
void scan_seg_kernel(const us* __restrict__ zx, const us* __restrict__ xc,
                     const float* __restrict__ dt_bias, const float* __restrict__ A_log,
                     const float* __restrict__ D_skip, float* __restrict__ y,
                     float* __restrict__ alpha, us* __restrict__ Hseg)
{
    __shared__ __attribute__((aligned(16))) float buf[SCHUNK][BUF_STRIDE];
    __shared__ float dtv_s[SCHUNK], dA_s[SCHUNK], acs[SCHUNK];
    __shared__ float carry_s;
    const int bi = blockIdx.x;
    const int bh = bi >> 3, seg = bi & 7;
    const int b = bh >> 5, h = bh & 31;
    const int t = threadIdx.x, p = t >> 3, ng = t & 7;
    const int t0g = seg * SEGLEN;
    const float dtb = dt_bias[h];
    const float Acoef = -expf(A_log[h]);
    const float Dsk = D_skip[h];
    if (t == 0) carry_s = 1.f;
    float s[16];
#pragma unroll
    for (int j = 0; j < 16; ++j) s[j] = 0.f;

    for (int c0 = 0; c0 < SEGLEN; c0 += SCHUNK) {
        __syncthreads();
        for (int idx = t; idx < SCHUNK * 320; idx += 512) {
            int sl = idx / 320, c = idx - sl * 320;
            const us* xr = xc + (size_t)(b * SEQ + t0g + c0 + sl) * CONV_DIM;
            float v;
            if (c < 64)       v = h2f(xr[h * 64 + c]);
            else if (c < 192) v = h2f(xr[D_INNER + (c - 64)]);
            else              v = h2f(xr[D_INNER + D_STATE + (c - 192)]);
            buf[sl][c] = v;
        }
        if (t < SCHUNK) {
            int row = b * SEQ + t0g + c0 + t;
            float dtraw = h2f(zx[(size_t)row * D_IN_PROJ + (D_IN_PROJ - NHEADS) + h]) + dtb;
            float dtv = (dtraw > 20.f) ? dtraw : log1pf(expf(dtraw));
            dtv_s[t] = dtv;
            dA_s[t] = expf(dtv * Acoef);
        }
        __syncthreads();
        if (t == 0) {
            float ac = carry_s;
#pragma unroll
            for (int i = 0; i < SCHUNK; ++i) { ac *= dA_s[i]; acs[i] = ac; }
            carry_s = ac;
        }
        __syncthreads();
        if (t < SCHUNK)
            alpha[(size_t)bh * SEQ + t0g + c0 + t] = acs[t];
        for (int sl = 0; sl < SCHUNK; ++sl) {
            float dA = dA_s[sl], dtv = dtv_s[sl];
            float xv = buf[sl][p];
            float xp = xv * dtv;
            float yp = 0.f;
#pragma unroll
            for (int q = 0; q < 4; ++q) {
                float4 Bv = *(const float4*)&buf[sl][64  + ng * 4 + q * 32];
                float4 Cv = *(const float4*)&buf[sl][192 + ng * 4 + q * 32];
                s[q*4+0] = fmaf(s[q*4+0], dA, xp * Bv.x); yp = fmaf(s[q*4+0], Cv.x, yp);
                s[q*4+1] = fmaf(s[q*4+1], dA, xp * Bv.y); yp = fmaf(s[q*4+1], Cv.y, yp);
                s[q*4+2] = fmaf(s[q*4+2], dA, xp * Bv.z); yp = fmaf(s[q*4+2], Cv.z, yp);
                s[q*4+3] = fmaf(s[q*4+3], dA, xp * Bv.w); yp = fmaf(s[q*4+3], Cv.w, yp);
            }
            yp += __shfl_down(yp, 4, 8);
            yp += __shfl_down(yp, 2, 8);
            yp += __shfl_down(yp, 1, 8);
            if (ng == 0)
                y[(size_t)(b * SEQ + t0g + c0 + sl) * D_INNER + h * 64 + p] = yp + Dsk * xv;
        }
    }
    us* hs = Hseg + ((size_t)bi * 64 + p) * 128;
#pragma unroll
    for (int q = 0; q < 4; ++q) {
        ushort4 o;
        o.x = f2h(s[q*4+0]); o.y = f2h(s[q*4+1]);
        o.z = f2h(s[q*4+2]); o.w = f2h(s[q*4+3]);
        *(ushort4*)(hs + ng * 4 + q * 32) = o;
    }
}

// ---------------------------------------------------------------------------
// PASS 2: sequential fixup across segments (in-place: Hseg -> Hin)
// ---------------------------------------------------------------------------
__global__ __launch_bounds__(512)
void state_fixup_kernel(const float* __restrict__ alpha, us* __restrict__ Hseg)
{
    const int bh = blockIdx.x;
    const int t = threadIdx.x, p = t >> 3, ng = t & 7;
    float carry[16];
#pragma unroll
    for (int j = 0; j < 16; ++j) carry[j] = 0.f;
    for (int seg = 0; seg < NSEG; ++seg) {
        us* hs = Hseg + (((size_t)bh * NSEG + seg) * 64 + p) * 128;
        float ae = alpha[(size_t)bh * SEQ + seg * SEGLEN + SEGLEN - 1];
        float tmp[16];
#pragma unroll
        for (int q = 0; q < 4; ++q) {
            ushort4 u = *(const ushort4*)(hs + ng * 4 + q * 32);
            tmp[q*4+0] = h2f(u.x); tmp[q*4+1] = h2f(u.y);
            tmp[q*4+2] = h2f(u.z); tmp[q*4+3] = h2f(u.w);
        }
#pragma unroll
        for (int q = 0; q < 4; ++q) {
            ushort4 o;
            o.x = f2h(carry[q*4+0]); o.y = f2h(carry[q*4+1]);
            o.z = f2h(carry[q*4+2]); o.w = f2h(carry[q*4+3]);
            *(ushort4*)(hs + ng * 4 + q * 32) = o;
        }
#pragma unroll
        for (int j = 0; j < 16; ++j) carry[j] = fmaf(carry[j], ae, tmp[j]);
    }
}

// ---------------------------------------------------------------------------
// PASS 3: y_t += alpha_t * (C_t . Hin_seg).  Segments 1..7 only.
// ---------------------------------------------------------------------------
__global__ __launch_bounds__(512)
void correct_kernel(const us* __restrict__ xc, const float* __restrict__ alpha,
                    const us* __restrict__ Hseg, float* __restrict__ y)
{
    __shared__ __attribute__((aligned(16))) float Csh[SCHUNK][132];
    __shared__ float ac_sh[SCHUNK];
    const int bi = blockIdx.x;
    const int bh = bi / 7, seg = 1 + (bi % 7);
    const int b = bh >> 5, h = bh & 31;
    const int t = threadIdx.x, p = t >> 3, ng = t & 7;
    const int t0g = seg * SEGLEN;

    float s[16];
    const us* hs = Hseg + (((size_t)bh * NSEG + seg) * 64 + p) * 128;
#pragma unroll
    for (int q = 0; q < 4; ++q) {
        ushort4 u = *(const ushort4*)(hs + ng * 4 + q * 32);
        s[q*4+0] = h2f(u.x); s[q*4+1] = h2f(u.y);
        s[q*4+2] = h2f(u.z); s[q*4+3] = h2f(u.w);
    }

    for (int c0 = 0; c0 < SEGLEN; c0 += SCHUNK) {
        __syncthreads();
        for (int idx = t; idx < SCHUNK * 128; idx += 512) {
            int sl = idx >> 7, c = idx & 127;
            Csh[sl][c] = h2f(xc[(size_t)(b * SEQ + t0g + c0 + sl) * CONV_DIM
                               + D_INNER + D_STATE + c]);
        }
        if (t < SCHUNK)
            ac_sh[t] = alpha[(size_t)bh * SEQ + t0g + c0 + t];
        __syncthreads();
        for (int sl = 0; sl < SCHUNK; ++sl) {
            float yp = 0.f;
#pragma unroll
            for (int q = 0; q < 4; ++q) {
                float4 Cv = *(const float4*)&Csh[sl][ng * 4 + q * 32];
                yp = fmaf(s[q*4+0], Cv.x, yp);
                yp = fmaf(s[q*4+1], Cv.y, yp);
                yp = fmaf(s[q*4+2], Cv.z, yp);
                yp = fmaf(s[q*4+3], Cv.w, yp);
            }
            yp += __shfl_down(yp, 4, 8);
            yp += __shfl_down(yp, 2, 8);
            yp += __shfl_down(yp, 1, 8);
            if (ng == 0) {
                size_t idx = (size_t)(b * SEQ + t0g + c0 + sl) * D_INNER + h * 64 + p;
                y[idx] += ac_sh[sl] * yp;
            }
        }
    }
}

// ---------------------------------------------------------------------------
// gated RMSNorm: y fp32 + z fp16 -> yn fp16
// ---------------------------------------------------------------------------
__global__ __launch_bounds__(256)
void gated_rmsnorm_kernel(const float* __restrict__ y,
                          const us* __restrict__ zxbcdt,
                          const float* __restrict__ norm_w,
                          us* __restrict__ yn)
{
    int bl = blockIdx.x;
    int t  = threadIdx.x;
    const float* yr = y + (size_t)bl * D_INNER;
    const us* zr = zxbcdt + (size_t)bl * D_IN_PROJ;
    us* outr = yn + (size_t)bl * D_INNER;

    float gv[8];
    float ss = 0.f;
#pragma unroll
    for (int q = 0; q < 8; ++q) {
        int j = t + q * 256;
        float z = h2f(zr[j]);
        float g = yr[j] * (z / (1.f + expf(-z)));
        gv[q] = g;
        ss += g * g;
    }
    __shared__ float red[256];
    red[t] = ss;
    __syncthreads();
    for (int w = 128; w > 0; w >>= 1) {
        if (t < w) red[t] += red[t + w];
        __syncthreads();
    }
    float rs = rsqrtf(red[0] / (float)D_INNER + 1e-5f);
#pragma unroll
    for (int q = 0; q < 8; ++q) {
        int j = t + q * 256;
        outr[j] = f2h(gv[q] * rs * norm_w[j]);
    }
}

// ---------------------------------------------------------------------------
// final: out[tok] = dot(t1[tok,:], w2[:,0]) + b2   (t1 fp16)
// ---------------------------------------------------------------------------
__global__ __launch_bounds__(256)
void final_dot_kernel(const us* __restrict__ t1,
                      const float* __restrict__ w2,
                      const float* __restrict__ b2,
                      float* __restrict__ out)
{
    int bl = blockIdx.x;
    int t  = threadIdx.x;
    float s = 0.f;
    for (int j = t; j < D_MODEL; j += 256)
        s = fmaf(h2f(t1[(size_t)bl * D_MODEL + j]), w2[j], s);
    __shared__ float red[256];
    red[t] = s;
    __syncthreads();
    for (int w = 128; w > 0; w >>= 1) {
        if (t < w) red[t] += red[t + w];
        __syncthreads();
    }
    if (t == 0) out[bl] = red[0] + b2[0];
}

// ---------------------------------------------------------------------------
extern "C" void kernel_launch(void* const* d_in, const int* in_sizes, int n_in,
                              void* d_out, int out_size, void* d_ws, size_t ws_size,
                              hipStream_t stream)
{
    const float* x        = (const float*)d_in[0];
    const float* steps    = (const float*)d_in[1];
    const float* curr     = (const float*)d_in[2];
    const float* mi_w1    = (const float*)d_in[3];
    const float* mi_b1    = (const float*)d_in[4];
    const float* mi_w2    = (const float*)d_in[5];
    const float* mi_b2    = (const float*)d_in[6];
    const float* W_in     = (const float*)d_in[7];
    const float* conv_w   = (const float*)d_in[8];
    const float* conv_b   = (const float*)d_in[9];
    const float* dt_bias  = (const float*)d_in[10];
    const float* A_log    = (const float*)d_in[11];
    const float* D_skip   = (const float*)d_in[12];
    const float* norm_w   = (const float*)d_in[13];
    const float* W_out    = (const float*)d_in[14];
    const float* mo_w1    = (const float*)d_in[15];
    const float* mo_b1    = (const float*)d_in[16];
    const float* mo_w2    = (const float*)d_in[17];
    const float* mo_b2    = (const float*)d_in[18];
    float* out = (float*)d_out;

    // ---- workspace layout (fp16 first, fp32 after) ----
    us* wt_mi1 = (us*)d_ws;                                 // [512][512]
    us* wt_mi2 = wt_mi1 + (size_t)512 * 512;                // [1024][512]
    us* wt_in  = wt_mi2 + (size_t)1024 * 512;               // 4 x [4480][1024]
    us* wt_out = wt_in  + (size_t)4 * NPAD_IN * 1024;       // 4 x [1024][2048]
    us* wt_mo1 = wt_out + (size_t)4 * 1024 * 2048;          // [1024][1024]
    us* Hseg   = wt_mo1 + (size_t)1024 * 1024;              // 128*8*64*128
    us* hcat   = Hseg   + (size_t)NBH * NSEG * 64 * 128;    // [2048][512]
    us* h      = hcat   + (size_t)NTOK * 512;               // [2048][1024]
    us* zxb    = h      + (size_t)NTOK * D_MODEL;           // [2048][4384]
    us* xc     = zxb    + (size_t)NTOK * D_IN_PROJ;         // [2048][2304]
    us* yn     = xc     + (size_t)NTOK * CONV_DIM;          // [2048][2048]
    us* t0     = zxb;                                       // alias (pre-block0)
    us* t1     = xc;                                        // alias (post-blocks)
    float* fbase = (float*)((((uintptr_t)(yn + (size_t)NTOK * D_INNER)) + 255)
                            & ~(uintptr_t)255);
    float* y     = fbase;                                   // [2048][2048] fp32
    float* alpha = y + (size_t)NTOK * D_INNER;              // [128][512]

    // ---- weight transposes (fp16) ----
    transpose_f16_kernel<<<dim3(512/32, 512/32), 256, 0, stream>>>(mi_w1, wt_mi1, 512, 512);
    transpose_f16_kernel<<<dim3(1024/32, 512/32), 256, 0, stream>>>(mi_w2, wt_mi2, 512, 1024);
    for (int i = 0; i < NBLOCKS; ++i) {
        transpose_f16_kernel<<<dim3(NPAD_IN/32, 1024/32), 256, 0, stream>>>(
            W_in + (size_t)i * D_MODEL * D_IN_PROJ, wt_in + (size_t)i * NPAD_IN * 1024,
            D_MODEL, D_IN_PROJ);
        transpose_f16_kernel<<<dim3(1024/32, 2048/32), 256, 0, stream>>>(
            W_out + (size_t)i * D_INNER * D_MODEL, wt_out + (size_t)i * 1024 * 2048,
            D_INNER, D_MODEL);
    }
    transpose_f16_kernel<<<dim3(1024/32, 1024/32), 256, 0, stream>>>(mo_w1, wt_mo1, 1024, 1024);

    // ---- forward ----
    concat_kernel<<<(NTOK * 512 + 255) / 256, 256, 0, stream>>>(x, steps, curr, hcat);

    mfma_gemm_f16<64, 2><<<dim3(512/64, NTOK/128), 256, 0, stream>>>(
        hcat, wt_mi1, mi_b1, t0, 512, 512, 1);
    mfma_gemm_f16<64, 2><<<dim3(1024/64, NTOK/128), 256, 0, stream>>>(
        t0, wt_mi2, mi_b2, h, 1024, 512, 0);

    for (int i = 0; i < NBLOCKS; ++i) {
        mfma_gemm_f16<128, 4><<<dim3(NPAD_IN/128, NTOK/128), 256, 0, stream>>>(
            h, wt_in + (size_t)i * NPAD_IN * 1024, nullptr, zxb, D_IN_PROJ, D_MODEL, 0);
        conv_silu_kernel<<<(NTOK * CONV_DIM + 255) / 256, 256, 0, stream>>>(
            zxb, conv_w + (size_t)i * CONV_DIM * DCONV, conv_b + (size_t)i * CONV_DIM, xc);
        scan_seg_kernel<<<NBH * NSEG, 512, 0, stream>>>(
            zxb, xc, dt_bias + i * NHEADS, A_log + i * NHEADS, D_skip + i * NHEADS,
            y, alpha, Hseg);
        state_fixup_kernel<<<NBH, 512, 0, stream>>>(alpha, Hseg);
        correct_kernel<<<NBH * (NSEG - 1), 512, 0, stream>>>(xc, alpha, Hseg, y);
        gated_rmsnorm_kernel<<<NTOK, 256, 0, stream>>>(
            y, zxb, norm_w + (size_t)i * D_INNER, yn);
        mfma_gemm_f16<64, 2><<<dim3(1024/64, NTOK/128), 256, 0, stream>>>(
            yn, wt_out + (size_t)i * 1024 * 2048, nullptr, h, 1024, 2048, 0);
    }

    mfma_gemm_f16<64, 2><<<dim3(1024/64, NTOK/128), 256, 0, stream>>>(
        h, wt_mo1, mo_b1, t1, 1024, 1024, 1);
    final_dot_kernel<<<NTOK, 256, 0, stream>>>(t1, mo_w2, mo_b2, out);
}

// Round 7
// 813.987 us; speedup vs baseline: 6.8763x; 1.4138x over previous
//
#include <hip/hip_runtime.h>
#include <hip/hip_bf16.h>
#include <math.h>

#define D_MODEL   1024
#define D_INNER   2048
#define D_STATE   128
#define NHEADS    32
#define HEADDIM   64
#define DCONV     4
#define CONV_DIM  (D_INNER + 2 * D_STATE)              // 2304
#define D_IN_PROJ (2 * D_INNER + 2 * D_STATE + NHEADS) // 4384
#define NBLOCKS   4
#define BATCH     4
#define SEQ       512
#define NTOK      (BATCH * SEQ)                        // 2048
#define STATE_IN  510
#define NPAD_IN   4480
#define NSEG      8
#define SEGLEN    64
#define NBH       (BATCH * NHEADS)                     // 128
#define OFF_B     D_INNER                              // 2048
#define OFF_C     (D_INNER + D_STATE)                  // 2176
#define OFF_DT    (D_IN_PROJ - NHEADS)

typedef _Float16 half8_t __attribute__((ext_vector_type(8)));
typedef float f32x4_t  __attribute__((ext_vector_type(4)));
typedef unsigned short us;

__device__ __forceinline__ us f2h(float f) {
    _Float16 h = (_Float16)f;
    return __builtin_bit_cast(us, h);
}
__device__ __forceinline__ float h2f(us u) {
    return (float)__builtin_bit_cast(_Float16, u);
}
__device__ __forceinline__ void gl2lds16(const us* gp, us* lp) {
    __builtin_amdgcn_global_load_lds(
        (const __attribute__((address_space(1))) unsigned int*)(gp),
        (__attribute__((address_space(3))) unsigned int*)(lp), 16, 0, 0);
}

// ---------------------------------------------------------------------------
// concat -> hcat [NTOK, 512] fp16
// ---------------------------------------------------------------------------
__global__ void concat_kernel(const float* __restrict__ x,
                              const float* __restrict__ steps,
                              const float* __restrict__ curr,
                              us* __restrict__ hcat)
{
    int idx = blockIdx.x * 256 + threadIdx.x;
    if (idx >= NTOK * 512) return;
    int bl = idx >> 9;
    int c  = idx & 511;
    float v;
    if (c < STATE_IN)       v = x[(size_t)bl * STATE_IN + c];
    else if (c == STATE_IN) v = steps[bl];
    else                    v = curr[bl];
    hcat[idx] = f2h(v);
}

// ---------------------------------------------------------------------------
// weight transpose + fp16 convert:  W[K,N] fp32 -> WT[Npad,K] fp16
// ---------------------------------------------------------------------------
__global__ __launch_bounds__(256)
void transpose_f16_kernel(const float* __restrict__ W, us* __restrict__ WT,
                          int K, int N)
{
    __shared__ us tile[32][36];
    int n0 = blockIdx.x * 32, k0 = blockIdx.y * 32;
    int t = threadIdx.x;
    int kl = t >> 3, nl = (t & 7) * 4;
    float4 v = make_float4(0.f, 0.f, 0.f, 0.f);
    if (n0 < N) v = *(const float4*)(W + (size_t)(k0 + kl) * N + n0 + nl);
    tile[nl + 0][kl] = f2h(v.x);
    tile[nl + 1][kl] = f2h(v.y);
    tile[nl + 2][kl] = f2h(v.z);
    tile[nl + 3][kl] = f2h(v.w);
    __syncthreads();
    int nl2 = t >> 3, kl2 = (t & 7) * 4;
    ushort4 o;
    o.x = tile[nl2][kl2 + 0];
    o.y = tile[nl2][kl2 + 1];
    o.z = tile[nl2][kl2 + 2];
    o.w = tile[nl2][kl2 + 3];
    *(ushort4*)(WT + (size_t)(n0 + nl2) * K + k0 + kl2) = o;
}

// ---------------------------------------------------------------------------
// fp16 MFMA GEMM with async global->LDS staging (unchanged from round 5)
// ---------------------------------------------------------------------------
template<int BN, int TI>
__global__ __launch_bounds__(256)
void mfma_gemm_f16(const us* __restrict__ A, const us* __restrict__ BT,
                   const float* __restrict__ bias, us* __restrict__ C,
                   int N, int K, int relu)
{
    __shared__ us Al[128 * 32];
    __shared__ us Bl[BN * 32];
    const int tid = threadIdx.x, lane = tid & 63, wave = tid >> 6;
    const int g = lane >> 4, l16 = lane & 15;
    const int wr = (BN == 128) ? (wave >> 1) * 64 : wave * 32;
    const int wc = (BN == 128) ? (wave & 1) * 64 : 0;
    const int m0 = blockIdx.y * 128, n0 = blockIdx.x * BN;
    const int lrow = lane >> 2;
    const int lcol = ((lane & 3) ^ ((lrow >> 2) & 3)) * 8;

    f32x4_t acc[TI][4];
    const f32x4_t zero = {0.f, 0.f, 0.f, 0.f};
#pragma unroll
    for (int i = 0; i < TI; ++i)
#pragma unroll
        for (int j = 0; j < 4; ++j) acc[i][j] = zero;

    const us* abase = A  + (size_t)m0 * K;
    const us* bbase = BT + (size_t)n0 * K;

    for (int k0 = 0; k0 < K; k0 += 32) {
        __syncthreads();
#pragma unroll
        for (int s = 0; s < 2; ++s) {
            int rb = wave * 32 + s * 16;
            gl2lds16(abase + (size_t)(rb + lrow) * K + k0 + lcol, &Al[rb * 32]);
        }
#pragma unroll
        for (int s = 0; s < BN / 64; ++s) {
            int rb = wave * (BN / 4) + s * 16;
            gl2lds16(bbase + (size_t)(rb + lrow) * K + k0 + lcol, &Bl[rb * 32]);
        }
        __syncthreads();
        half8_t af[TI], bfr[4];
#pragma unroll
        for (int ti = 0; ti < TI; ++ti) {
            int r = wr + ti * 16 + l16;
            af[ti] = *(const half8_t*)&Al[r * 32 + ((g ^ ((r >> 2) & 3)) * 8)];
        }
#pragma unroll
        for (int tj = 0; tj < 4; ++tj) {
            int r = wc + tj * 16 + l16;
            bfr[tj] = *(const half8_t*)&Bl[r * 32 + ((g ^ ((r >> 2) & 3)) * 8)];
        }
#pragma unroll
        for (int ti = 0; ti < TI; ++ti)
#pragma unroll
            for (int tj = 0; tj < 4; ++tj)
                acc[ti][tj] = __builtin_amdgcn_mfma_f32_16x16x32_f16(
                    af[ti], bfr[tj], acc[ti][tj], 0, 0, 0);
    }

#pragma unroll
    for (int tj = 0; tj < 4; ++tj) {
        int col = n0 + wc + tj * 16 + l16;
        if (col >= N) continue;
        float bv = bias ? bias[col] : 0.f;
#pragma unroll
        for (int ti = 0; ti < TI; ++ti) {
            int rbase = m0 + wr + ti * 16 + g * 4;
#pragma unroll
            for (int r = 0; r < 4; ++r) {
                float v = acc[ti][tj][r] + bv;
                if (relu) v = fmaxf(v, 0.f);
                C[(size_t)(rbase + r) * N + col] = f2h(v);
            }
        }
    }
}

// ---------------------------------------------------------------------------
// causal depthwise conv1d (k=4) + SiLU; fp16 in/out, fp32 math
// ---------------------------------------------------------------------------
__global__ void conv_silu_kernel(const us* __restrict__ zxbcdt,
                                 const float* __restrict__ cw,
                                 const float* __restrict__ cb,
                                 us* __restrict__ xBCc)
{
    int idx = blockIdx.x * 256 + threadIdx.x;
    if (idx >= NTOK * CONV_DIM) return;
    int c  = idx % CONV_DIM;
    int bl = idx / CONV_DIM;
    int b  = bl >> 9;
    int l  = bl & 511;
    float acc = cb[c];
#pragma unroll
    for (int k = 0; k < DCONV; ++k) {
        int ll = l + k - (DCONV - 1);
        if (ll >= 0)
            acc = fmaf(h2f(zxbcdt[(size_t)(b * SEQ + ll) * D_IN_PROJ + D_INNER + c]),
                       cw[c * DCONV + k], acc);
    }
    xBCc[idx] = f2h(acc / (1.f + expf(-acc)));
}

// ---------------------------------------------------------------------------
// PASS 1 (MFMA chunked SSD): one block per (b,h,seg); 256 threads = 4 waves.
// G = C.B^T (64x64,K=128); S' = mask/decay-scale(G) + Dsk on diag;
// Y = S'.X (K=64) -> y global; H_local^T[p][n] = sum_j X[j][p] csc_j B[j][n]
// (64x128, K=64) -> Hseg. alpha_i = exp(cumsum log dA) -> global.
// LDS swizzle: granule (16B) phys = logical ^ (row & 7)  -> 2-way (free).
// Ssh ALIASES Csh (dead after P1); extra barrier separates last Csh read
// from S' write. Static LDS total 56.75 KB (< 64 KB limit).
// ---------------------------------------------------------------------------
__global__ __launch_bounds__(256)
void scan_seg_mfma_kernel(const us* __restrict__ zx, const us* __restrict__ xc,
                          const float* __restrict__ dt_bias,
                          const float* __restrict__ A_log,
                          const float* __restrict__ D_skip,
                          float* __restrict__ y, float* __restrict__ alpha,
                          us* __restrict__ Hseg)
{
    __shared__ __attribute__((aligned(16))) us Csh[64 * 128];  // P1 A; aliased by Ssh
    __shared__ __attribute__((aligned(16))) us Bsh[64 * 128];  // P1 B
    __shared__ __attribute__((aligned(16))) us Bt[128 * 64];   // B^T [n][j], P3
    __shared__ __attribute__((aligned(16))) us Xt[64 * 64];    // X^T [p][j], P2/P3
    __shared__ float dt_s[64], ls[64], csc[64];
    us* Ssh = Csh;                                             // S' [i][j] (8 KB of 16)
    const int bi = blockIdx.x, bh = bi >> 3, seg = bi & 7;
    const int b = bh >> 5, h = bh & 31;
    const int tid = threadIdx.x, lane = tid & 63, w = tid >> 6;
    const int g = lane >> 4, l16 = lane & 15;
    const int t0g = seg * SEGLEN;
    const size_t rowbase = (size_t)(b * SEQ + t0g);

    // --- async DMA staging of C and B tiles (row-major, swizzled) ---
    {
        int rr = lane >> 4, s = lane & 15;
#pragma unroll
        for (int it = 0; it < 4; ++it) {
            int rb = w * 16 + it * 4;
            int row = rb + rr;
            const us* src = xc + (rowbase + row) * CONV_DIM;
            int sw = (s ^ (row & 7)) * 8;
            gl2lds16(src + OFF_C + sw, &Csh[rb * 128]);
            gl2lds16(src + OFF_B + sw, &Bsh[rb * 128]);
        }
    }
    // --- VGPR transpose staging: Xt[p][j] ---
#pragma unroll
    for (int qi = 0; qi < 4; ++qi) {
        int idx = tid + qi * 256;          // 1024 quads
        int pq = idx & 15, j = idx >> 4;
        ushort4 v = *(const ushort4*)(xc + (rowbase + j) * CONV_DIM + h * 64 + pq * 4);
#pragma unroll
        for (int e = 0; e < 4; ++e) {
            int p = pq * 4 + e;
            int pc = ((((j >> 3) ^ (p & 7)) << 3) | (j & 7));
            Xt[p * 64 + pc] = ((const us*)&v)[e];
        }
    }
    // --- VGPR transpose staging: Bt[n][j] ---
#pragma unroll
    for (int qi = 0; qi < 8; ++qi) {
        int idx = tid + qi * 256;          // 2048 quads
        int nq = idx & 31, j = idx >> 5;
        ushort4 v = *(const ushort4*)(xc + (rowbase + j) * CONV_DIM + OFF_B + nq * 4);
#pragma unroll
        for (int e = 0; e < 4; ++e) {
            int n = nq * 4 + e;
            int pc = ((((j >> 3) ^ (n & 7)) << 3) | (j & 7));
            Bt[n * 64 + pc] = ((const us*)&v)[e];
        }
    }
    // --- dt / cumulative decay (wave 0) ---
    if (tid < 64) {
        int j = tid;
        float dtraw = h2f(zx[(rowbase + j) * D_IN_PROJ + OFF_DT + h]) + dt_bias[h];
        float dtv = (dtraw > 20.f) ? dtraw : log1pf(expf(dtraw));
        float ld = dtv * (-expf(A_log[h]));
#pragma unroll
        for (int o = 1; o < 64; o <<= 1) {
            float v = __shfl_up(ld, o);
            if (j >= o) ld += v;
        }
        float al = expf(ld);
        dt_s[j] = dtv;
        ls[j] = ld;
        alpha[(size_t)bh * SEQ + t0g + j] = al;
        float cend = __shfl(ld, 63);
        csc[j] = dtv * expf(cend - ld);
    }
    __syncthreads();   // DMA drained (vmcnt0 before barrier) + stagings visible

    const float Dsk = D_skip[h];
    const f32x4_t vzero = {0.f, 0.f, 0.f, 0.f};

    // --- P1: G = C.B^T ---
    f32x4_t acc1[4];
#pragma unroll
    for (int jt = 0; jt < 4; ++jt) acc1[jt] = vzero;
    {
        int ia = w * 16 + l16;
#pragma unroll
        for (int ks = 0; ks < 4; ++ks) {
            half8_t a = *(const half8_t*)&Csh[ia * 128 + (((ks * 4 + g) ^ (ia & 7)) << 3)];
#pragma unroll
            for (int jt = 0; jt < 4; ++jt) {
                int jr = jt * 16 + l16;
                half8_t bfr = *(const half8_t*)&Bsh[jr * 128 + (((ks * 4 + g) ^ (jr & 7)) << 3)];
                acc1[jt] = __builtin_amdgcn_mfma_f32_16x16x32_f16(a, bfr, acc1[jt], 0, 0, 0);
            }
        }
    }
    __syncthreads();   // all waves done reading Csh before Ssh overwrites it

    // --- S' mask/scale -> Ssh (aliases Csh) ---
    {
        int i0 = w * 16 + g * 4;
        float lsi[4];
#pragma unroll
        for (int r = 0; r < 4; ++r) lsi[r] = ls[i0 + r];
#pragma unroll
        for (int jt = 0; jt < 4; ++jt) {
            int j = jt * 16 + l16;
            float lj = ls[j], dj = dt_s[j];
#pragma unroll
            for (int r = 0; r < 4; ++r) {
                int i = i0 + r;
                float v = 0.f;
                if (j < i)       v = acc1[jt][r] * dj * expf(lsi[r] - lj);
                else if (j == i) v = acc1[jt][r] * dj + Dsk;
                int pc = ((((j >> 3) ^ (i & 7)) << 3) | (j & 7));
                Ssh[i * 64 + pc] = f2h(v);
            }
        }
    }
    __syncthreads();

    // --- P2: Y = S'.X ---
    f32x4_t acc2[4];
#pragma unroll
    for (int nt = 0; nt < 4; ++nt) acc2[nt] = vzero;
    {
        int ia = w * 16 + l16;
#pragma unroll
        for (int ks = 0; ks < 2; ++ks) {
            half8_t a = *(const half8_t*)&Ssh[ia * 64 + (((ks * 4 + g) ^ (ia & 7)) << 3)];
#pragma unroll
            for (int nt = 0; nt < 4; ++nt) {
                int pr = nt * 16 + l16;
                half8_t bfr = *(const half8_t*)&Xt[pr * 64 + (((ks * 4 + g) ^ (pr & 7)) << 3)];
                acc2[nt] = __builtin_amdgcn_mfma_f32_16x16x32_f16(a, bfr, acc2[nt], 0, 0, 0);
            }
        }
    }
    {
        int i0 = w * 16 + g * 4;
#pragma unroll
        for (int nt = 0; nt < 4; ++nt) {
            int p = nt * 16 + l16;
#pragma unroll
            for (int r = 0; r < 4; ++r)
                y[(rowbase + i0 + r) * D_INNER + h * 64 + p] = acc2[nt][r];
        }
    }
    // --- P3: H_local^T[p][n] = (csc-scaled Xt) . Bt ---
    f32x4_t acc3[8];
#pragma unroll
    for (int nt = 0; nt < 8; ++nt) acc3[nt] = vzero;
    {
        int pa = w * 16 + l16;
#pragma unroll
        for (int ks = 0; ks < 2; ++ks) {
            half8_t araw = *(const half8_t*)&Xt[pa * 64 + (((ks * 4 + g) ^ (pa & 7)) << 3)];
            half8_t a;
#pragma unroll
            for (int e = 0; e < 8; ++e)
                a[e] = (_Float16)((float)araw[e] * csc[ks * 32 + g * 8 + e]);
#pragma unroll
            for (int nt = 0; nt < 8; ++nt) {
                int nr = nt * 16 + l16;
                half8_t bfr = *(const half8_t*)&Bt[nr * 64 + (((ks * 4 + g) ^ (nr & 7)) << 3)];
                acc3[nt] = __builtin_amdgcn_mfma_f32_16x16x32_f16(a, bfr, acc3[nt], 0, 0, 0);
            }
        }
    }
    {
        int p0 = w * 16 + g * 4;
#pragma unroll
        for (int nt = 0; nt < 8; ++nt) {
            int n = nt * 16 + l16;
#pragma unroll
            for (int r = 0; r < 4; ++r)
                Hseg[((size_t)bi * 64 + p0 + r) * 128 + n] = f2h(acc3[nt][r]);
        }
    }
}

// ---------------------------------------------------------------------------
// PASS 2: sequential fixup across segments (in-place: Hseg -> Hin)
// ---------------------------------------------------------------------------
__global__ __launch_bounds__(512)
void state_fixup_kernel(const float* __restrict__ alpha, us* __restrict__ Hseg)
{
    const int bh = blockIdx.x;
    const int t = threadIdx.x, p = t >> 3, ng = t & 7;
    float carry[16];
#pragma unroll
    for (int j = 0; j < 16; ++j) carry[j] = 0.f;
    for (int seg = 0; seg < NSEG; ++seg) {
        us* hs = Hseg + (((size_t)bh * NSEG + seg) * 64 + p) * 128;
        float ae = alpha[(size_t)bh * SEQ + seg * SEGLEN + SEGLEN - 1];
        float tmp[16];
#pragma unroll
        for (int q = 0; q < 4; ++q) {
            ushort4 u = *(const ushort4*)(hs + ng * 4 + q * 32);
            tmp[q*4+0] = h2f(u.x); tmp[q*4+1] = h2f(u.y);
            tmp[q*4+2] = h2f(u.z); tmp[q*4+3] = h2f(u.w);
        }
#pragma unroll
        for (int q = 0; q < 4; ++q) {
            ushort4 o;
            o.x = f2h(carry[q*4+0]); o.y = f2h(carry[q*4+1]);
            o.z = f2h(carry[q*4+2]); o.w = f2h(carry[q*4+3]);
            *(ushort4*)(hs + ng * 4 + q * 32) = o;
        }
#pragma unroll
        for (int j = 0; j < 16; ++j) carry[j] = fmaf(carry[j], ae, tmp[j]);
    }
}

// ---------------------------------------------------------------------------
// PASS 3 (MFMA): y += alpha_i * (C . Hin^T).  One block per (b,h,seg-1).
// ---------------------------------------------------------------------------
__global__ __launch_bounds__(256)
void correct_mfma_kernel(const us* __restrict__ xc, const float* __restrict__ alpha,
                         const us* __restrict__ Hseg, float* __restrict__ y)
{
    __shared__ __attribute__((aligned(16))) us Csh[64 * 128];
    __shared__ __attribute__((aligned(16))) us Hsh[64 * 128];
    __shared__ float als_s[64];
    const int bi = blockIdx.x;
    const int bh = bi / 7, seg = 1 + (bi % 7);
    const int b = bh >> 5, h = bh & 31;
    const int tid = threadIdx.x, lane = tid & 63, w = tid >> 6;
    const int g = lane >> 4, l16 = lane & 15;
    const int t0g = seg * SEGLEN;
    const size_t rowbase = (size_t)(b * SEQ + t0g);
    const size_t hbase = (size_t)(bh * NSEG + seg) * 64;

    {
        int rr = lane >> 4, s = lane & 15;
#pragma unroll
        for (int it = 0; it < 4; ++it) {
            int rb = w * 16 + it * 4;
            int row = rb + rr;
            int sw = (s ^ (row & 7)) * 8;
            gl2lds16(xc + (rowbase + row) * CONV_DIM + OFF_C + sw, &Csh[rb * 128]);
            gl2lds16(Hseg + (hbase + row) * 128 + sw, &Hsh[rb * 128]);
        }
    }
    if (tid < 64) als_s[tid] = alpha[(size_t)bh * SEQ + t0g + tid];
    __syncthreads();

    const f32x4_t vzero = {0.f, 0.f, 0.f, 0.f};
    f32x4_t acc[4];
#pragma unroll
    for (int nt = 0; nt < 4; ++nt) acc[nt] = vzero;
    int ia = w * 16 + l16;
#pragma unroll
    for (int ks = 0; ks < 4; ++ks) {
        half8_t a = *(const half8_t*)&Csh[ia * 128 + (((ks * 4 + g) ^ (ia & 7)) << 3)];
#pragma unroll
        for (int nt = 0; nt < 4; ++nt) {
            int pr = nt * 16 + l16;
            half8_t bfr = *(const half8_t*)&Hsh[pr * 128 + (((ks * 4 + g) ^ (pr & 7)) << 3)];
            acc[nt] = __builtin_amdgcn_mfma_f32_16x16x32_f16(a, bfr, acc[nt], 0, 0, 0);
        }
    }
    int i0 = w * 16 + g * 4;
#pragma unroll
    for (int nt = 0; nt < 4; ++nt) {
        int p = nt * 16 + l16;
#pragma unroll
        for (int r = 0; r < 4; ++r) {
            size_t idx = (rowbase + i0 + r) * D_INNER + h * 64 + p;
            y[idx] += als_s[i0 + r] * acc[nt][r];
        }
    }
}

// ---------------------------------------------------------------------------
// gated RMSNorm: y fp32 + z fp16 -> yn fp16
// ---------------------------------------------------------------------------
__global__ __launch_bounds__(256)
void gated_rmsnorm_kernel(const float* __restrict__ y,
                          const us* __restrict__ zxbcdt,
                          const float* __restrict__ norm_w,
                          us* __restrict__ yn)
{
    int bl = blockIdx.x;
    int t  = threadIdx.x;
    const float* yr = y + (size_t)bl * D_INNER;
    const us* zr = zxbcdt + (size_t)bl * D_IN_PROJ;
    us* outr = yn + (size_t)bl * D_INNER;

    float gv[8];
    float ss = 0.f;
#pragma unroll
    for (int q = 0; q < 8; ++q) {
        int j = t + q * 256;
        float z = h2f(zr[j]);
        float g = yr[j] * (z / (1.f + expf(-z)));
        gv[q] = g;
        ss += g * g;
    }
    __shared__ float red[256];
    red[t] = ss;
    __syncthreads();
    for (int w = 128; w > 0; w >>= 1) {
        if (t < w) red[t] += red[t + w];
        __syncthreads();
    }
    float rs = rsqrtf(red[0] / (float)D_INNER + 1e-5f);
#pragma unroll
    for (int q = 0; q < 8; ++q) {
        int j = t + q * 256;
        outr[j] = f2h(gv[q] * rs * norm_w[j]);
    }
}

// ---------------------------------------------------------------------------
// final: out[tok] = dot(t1[tok,:], w2[:,0]) + b2   (t1 fp16)
// ---------------------------------------------------------------------------
__global__ __launch_bounds__(256)
void final_dot_kernel(const us* __restrict__ t1,
                      const float* __restrict__ w2,
                      const float* __restrict__ b2,
                      float* __restrict__ out)
{
    int bl = blockIdx.x;
    int t  = threadIdx.x;
    float s = 0.f;
    for (int j = t; j < D_MODEL; j += 256)
        s = fmaf(h2f(t1[(size_t)bl * D_MODEL + j]), w2[j], s);
    __shared__ float red[256];
    red[t] = s;
    __syncthreads();
    for (int w = 128; w > 0; w >>= 1) {
        if (t < w) red[t] += red[t + w];
        __syncthreads();
    }
    if (t == 0) out[bl] = red[0] + b2[0];
}

// ---------------------------------------------------------------------------
extern "C" void kernel_launch(void* const* d_in, const int* in_sizes, int n_in,
                              void* d_out, int out_size, void* d_ws, size_t ws_size,
                              hipStream_t stream)
{
    const float* x        = (const float*)d_in[0];
    const float* steps    = (const float*)d_in[1];
    const float* curr     = (const float*)d_in[2];
    const float* mi_w1    = (const float*)d_in[3];
    const float* mi_b1    = (const float*)d_in[4];
    const float* mi_w2    = (const float*)d_in[5];
    const float* mi_b2    = (const float*)d_in[6];
    const float* W_in     = (const float*)d_in[7];
    const float* conv_w   = (const float*)d_in[8];
    const float* conv_b   = (const float*)d_in[9];
    const float* dt_bias  = (const float*)d_in[10];
    const float* A_log    = (const float*)d_in[11];
    const float* D_skip   = (const float*)d_in[12];
    const float* norm_w   = (const float*)d_in[13];
    const float* W_out    = (const float*)d_in[14];
    const float* mo_w1    = (const float*)d_in[15];
    const float* mo_b1    = (const float*)d_in[16];
    const float* mo_w2    = (const float*)d_in[17];
    const float* mo_b2    = (const float*)d_in[18];
    float* out = (float*)d_out;

    // ---- workspace layout ----
    us* wt_mi1 = (us*)d_ws;
    us* wt_mi2 = wt_mi1 + (size_t)512 * 512;
    us* wt_in  = wt_mi2 + (size_t)1024 * 512;
    us* wt_out = wt_in  + (size_t)4 * NPAD_IN * 1024;
    us* wt_mo1 = wt_out + (size_t)4 * 1024 * 2048;
    us* Hseg   = wt_mo1 + (size_t)1024 * 1024;
    us* hcat   = Hseg   + (size_t)NBH * NSEG * 64 * 128;
    us* h      = hcat   + (size_t)NTOK * 512;
    us* zxb    = h      + (size_t)NTOK * D_MODEL;
    us* xc     = zxb    + (size_t)NTOK * D_IN_PROJ;
    us* yn     = xc     + (size_t)NTOK * CONV_DIM;
    us* t0     = zxb;
    us* t1     = xc;
    float* fbase = (float*)((((uintptr_t)(yn + (size_t)NTOK * D_INNER)) + 255)
                            & ~(uintptr_t)255);
    float* y     = fbase;
    float* alpha = y + (size_t)NTOK * D_INNER;

    // ---- weight transposes (fp16) ----
    transpose_f16_kernel<<<dim3(512/32, 512/32), 256, 0, stream>>>(mi_w1, wt_mi1, 512, 512);
    transpose_f16_kernel<<<dim3(1024/32, 512/32), 256, 0, stream>>>(mi_w2, wt_mi2, 512, 1024);
    for (int i = 0; i < NBLOCKS; ++i) {
        transpose_f16_kernel<<<dim3(NPAD_IN/32, 1024/32), 256, 0, stream>>>(
            W_in + (size_t)i * D_MODEL * D_IN_PROJ, wt_in + (size_t)i * NPAD_IN * 1024,
            D_MODEL, D_IN_PROJ);
        transpose_f16_kernel<<<dim3(1024/32, 2048/32), 256, 0, stream>>>(
            W_out + (size_t)i * D_INNER * D_MODEL, wt_out + (size_t)i * 1024 * 2048,
            D_INNER, D_MODEL);
    }
    transpose_f16_kernel<<<dim3(1024/32, 1024/32), 256, 0, stream>>>(mo_w1, wt_mo1, 1024, 1024);

    // ---- forward ----
    concat_kernel<<<(NTOK * 512 + 255) / 256, 256, 0, stream>>>(x, steps, curr, hcat);

    mfma_gemm_f16<64, 2><<<dim3(512/64, NTOK/128), 256, 0, stream>>>(
        hcat, wt_mi1, mi_b1, t0, 512, 512, 1);
    mfma_gemm_f16<64, 2><<<dim3(1024/64, NTOK/128), 256, 0, stream>>>(
        t0, wt_mi2, mi_b2, h, 1024, 512, 0);

    for (int i = 0; i < NBLOCKS; ++i) {
        mfma_gemm_f16<128, 4><<<dim3(NPAD_IN/128, NTOK/128), 256, 0, stream>>>(
            h, wt_in + (size_t)i * NPAD_IN * 1024, nullptr, zxb, D_IN_PROJ, D_MODEL, 0);
        conv_silu_kernel<<<(NTOK * CONV_DIM + 255) / 256, 256, 0, stream>>>(
            zxb, conv_w + (size_t)i * CONV_DIM * DCONV, conv_b + (size_t)i * CONV_DIM, xc);
        scan_seg_mfma_kernel<<<NBH * NSEG, 256, 0, stream>>>(
            zxb, xc, dt_bias + i * NHEADS, A_log + i * NHEADS, D_skip + i * NHEADS,
            y, alpha, Hseg);
        state_fixup_kernel<<<NBH, 512, 0, stream>>>(alpha, Hseg);
        correct_mfma_kernel<<<NBH * (NSEG - 1), 256, 0, stream>>>(xc, alpha, Hseg, y);
        gated_rmsnorm_kernel<<<NTOK, 256, 0, stream>>>(
            y, zxb, norm_w + (size_t)i * D_INNER, yn);
        mfma_gemm_f16<64, 2><<<dim3(1024/64, NTOK/128), 256, 0, stream>>>(
            yn, wt_out + (size_t)i * 1024 * 2048, nullptr, h, 1024, 2048, 0);
    }

    mfma_gemm_f16<64, 2><<<dim3(1024/64, NTOK/128), 256, 0, stream>>>(
        h, wt_mo1, mo_b1, t1, 1024, 1024, 1);
    final_dot_kernel<<<NTOK, 256, 0, stream>>>(t1, mo_w2, mo_b2, out);
}